// Round 6
// baseline (5194.188 us; speedup 1.0000x reference)
//
#include <hip/hip_runtime.h>
#include <hip/hip_bf16.h>
#include <math.h>

#define NN 20000
#define NE 320000

typedef __hip_bfloat16 bf16;
typedef unsigned short ushort_t;

__device__ __forceinline__ float b2f(bf16 v){ return __bfloat162float(v); }
__device__ __forceinline__ bf16 f2b(float v){ return __float2bfloat16(v); }
__device__ __forceinline__ int clampi(int v, int lo, int hi){ return v < lo ? lo : (v > hi ? hi : v); }

// dual-dtype load of a "float input" buffer: isf=1 -> f32, isf=0 -> bf16
__device__ __forceinline__ float ldf(const void* p, size_t i, int isf){
  return isf ? ((const float*)p)[i] : b2f(((const bf16*)p)[i]);
}

// ---- diagnostic fill (f32 out) -------------------------------------------
__global__ void fill_k(float* __restrict__ out, int n, float val){
  int i = blockIdx.x*blockDim.x + threadIdx.x;
  if (i < n) out[i] = val;
}

// ---- input dtype detection ------------------------------------------------
__global__ void detect_k(const ushort_t* __restrict__ xb, int* __restrict__ flag){
  if (blockIdx.x == 0 && threadIdx.x == 0){
    int cnt = 0;
    for (int i = 0; i < 256; i++){
      int e = (xb[i] >> 7) & 0xFF;
      if (e >= 112 && e <= 135) cnt++;
    }
    flag[0] = (cnt >= 220) ? 0 : 1;   // 0 = bf16 buffer, 1 = f32 buffer
    flag[1] = 0;                      // constant: internal bf16 buffers
  }
}

// ---- CSR build -----------------------------------------------------------

__global__ void count_k(const int* __restrict__ ei, int* __restrict__ cnt, int E){
  int e = blockIdx.x*blockDim.x + threadIdx.x;
  if (e < E){
    int d = clampi(ei[E + e], 0, NN-1);
    atomicAdd(&cnt[d], 1);
  }
}

__global__ void exscan_k(const int* __restrict__ cnt, int* __restrict__ off, int n){
  __shared__ int wtot[16];
  __shared__ int carrysh;
  int tid = threadIdx.x, lane = tid & 63, w = tid >> 6;
  if (tid == 0) carrysh = 0;
  __syncthreads();
  for (int base = 0; base < n; base += 1024){
    int i = base + tid;
    int v = (i < n) ? cnt[i] : 0;
    int s = v;
#pragma unroll
    for (int d = 1; d < 64; d <<= 1){
      int t = __shfl_up(s, d);
      if (lane >= d) s += t;
    }
    if (lane == 63) wtot[w] = s;
    __syncthreads();
    int woff = 0;
    for (int j = 0; j < w; j++) woff += wtot[j];
    int c = carrysh;
    if (i < n) off[i] = c + woff + s - v;   // exclusive prefix
    __syncthreads();
    if (tid == 1023) carrysh = c + woff + s;
    __syncthreads();
  }
  if (threadIdx.x == 0) off[n] = carrysh;
}

__global__ void scatter_k(const int* __restrict__ ei, int* __restrict__ cur,
                          int* __restrict__ perm, int E){
  int e = blockIdx.x*blockDim.x + threadIdx.x;
  if (e >= E) return;
  int d = clampi(ei[E + e], 0, NN-1);
  int p = atomicAdd(&cur[d], 1);
  if (p >= 0 && p < E) perm[p] = e;
}

// ---- GEMM: Out[m, ocol+n] = sum_k X[m,k]*W[k, wcol+n] + B[wcol+n] --------
// X dual-dtype (xflag), W/B dual-dtype (wflag), bf16 out.
template<int ROWS>
__global__ void gemm_bias(const void* __restrict__ X, const void* __restrict__ W,
                          const void* __restrict__ B, bf16* __restrict__ Out,
                          int K, int Dt, int wcol, int ldW, int ocol, int ldO,
                          const int* __restrict__ xflag, const int* __restrict__ wflag){
  int isx = xflag[0], isw = wflag[0];
  int n = blockIdx.x*64 + threadIdx.x;
  if (n >= Dt) return;
  size_t m0 = (size_t)blockIdx.y * ROWS;
  float bias = ldf(B, wcol + n, isw);
  float acc[ROWS];
#pragma unroll
  for (int r = 0; r < ROWS; r++) acc[r] = bias;
  for (int k = 0; k < K; k++){
    float wv = ldf(W, (size_t)k*ldW + wcol + n, isw);
#pragma unroll
    for (int r = 0; r < ROWS; r++) acc[r] += ldf(X, (m0 + r)*K + k, isx) * wv;
  }
#pragma unroll
  for (int r = 0; r < ROWS; r++) Out[(m0 + r)*(size_t)ldO + ocol + n] = f2b(acc[r]);
}

// ---- edge logits: one wave per sorted edge (Dt = CPL*64 tile) ------------
template<int CPL, int H>
__global__ void edge_logits(const bf16* __restrict__ Q, const bf16* __restrict__ Kf,
                            const int* __restrict__ ei, const int* __restrict__ perm,
                            bf16* __restrict__ LOG, float scale){
  int pos = blockIdx.x*4 + (threadIdx.x >> 6);
  if (pos >= NE) return;
  constexpr int D = CPL*64;
  constexpr int LPH = 64 / H;           // lanes per head
  int lane = threadIdx.x & 63;
  int e = perm[pos];
  int s = ei[e], d = ei[NE + e];
  const bf16* qr = Q  + (size_t)d*D + lane*CPL;
  const bf16* kr = Kf + (size_t)s*D + lane*CPL;
  float v = 0.f;
#pragma unroll
  for (int j = 0; j < CPL; j++) v += b2f(qr[j])*b2f(kr[j]);
#pragma unroll
  for (int off = 1; off < LPH; off <<= 1) v += __shfl_xor(v, off);
  if ((lane & (LPH-1)) == 0) LOG[(size_t)pos*H + lane/LPH] = f2b(v*scale);
}

// ---- per-(node,head) segment max + exp-sum -------------------------------
template<int H>
__global__ void seg_maxsum(const bf16* __restrict__ LOG, const int* __restrict__ off,
                           float* __restrict__ Mx, float* __restrict__ Dn){
  int t = blockIdx.x*blockDim.x + threadIdx.x;
  if (t >= NN*H) return;
  int node = t / H, h = t % H;
  int s = off[node], e = off[node+1];
  float m = -INFINITY;
  for (int i = s; i < e; i++) m = fmaxf(m, b2f(LOG[(size_t)i*H + h]));
  float den = 0.f;
  for (int i = s; i < e; i++) den += expf(b2f(LOG[(size_t)i*H + h]) - m);
  Mx[t] = m; Dn[t] = den;
}

// ---- alpha (in-place over LOG), optional f32 scatter to orig edge order --
template<int H>
__global__ void alpha_k(bf16* __restrict__ LOG, const float* __restrict__ Mx,
                        const float* __restrict__ Dn, const int* __restrict__ ei,
                        const int* __restrict__ perm, float* __restrict__ attn){
  size_t t = (size_t)blockIdx.x*blockDim.x + threadIdx.x;
  if (t >= (size_t)NE*H) return;
  int pos = (int)(t / H); int h = (int)(t % H);
  int e = perm[pos];
  int node = ei[NE + e];
  float a = expf(b2f(LOG[t]) - Mx[node*H + h]) / (Dn[node*H + h] + 1e-16f);
  LOG[t] = f2b(a);
  if (attn) attn[(size_t)e*H + h] = a;
}

// ---- aggregate: Xout[node, col+c] += sum_e alpha * V[src,c] (one wave) ---
template<int CPL, int H>
__global__ void aggregate(const bf16* __restrict__ V, const bf16* __restrict__ alpha,
                          const int* __restrict__ ei, const int* __restrict__ perm,
                          const int* __restrict__ off, bf16* __restrict__ Xout,
                          int ldO, int col0){
  int node = blockIdx.x*4 + (threadIdx.x >> 6);
  if (node >= NN) return;
  constexpr int D = CPL*64;
  constexpr int LPH = 64 / H;
  int lane = threadIdx.x & 63;
  int head = lane / LPH;
  float acc[CPL];
#pragma unroll
  for (int j = 0; j < CPL; j++) acc[j] = 0.f;
  int s0 = off[node], e0 = off[node+1];
  for (int i = s0; i < e0; i++){
    float a = b2f(alpha[(size_t)i*H + head]);
    const bf16* vr = V + (size_t)ei[perm[i]]*D + lane*CPL;
#pragma unroll
    for (int j = 0; j < CPL; j++) acc[j] += a * b2f(vr[j]);
  }
  bf16* o = Xout + (size_t)node*ldO + col0 + lane*CPL;
#pragma unroll
  for (int j = 0; j < CPL; j++) o[j] = f2b(b2f(o[j]) + acc[j]);
}

// ---- fused exact-GELU + LayerNorm, in place on bf16 ----------------------
template<int CPL>
__global__ void gelu_ln_ip(bf16* __restrict__ X, const void* __restrict__ G,
                           const void* __restrict__ Bt, const int* __restrict__ wflag){
  int isw = wflag[0];
  int node = blockIdx.x*4 + (threadIdx.x >> 6);
  if (node >= NN) return;
  constexpr int D = CPL*64;
  int lane = threadIdx.x & 63;
  bf16* xr = X + (size_t)node*D + lane*CPL;
  float v[CPL]; float s = 0.f;
#pragma unroll
  for (int j = 0; j < CPL; j++){
    float t = b2f(xr[j]);
    float ge = 0.5f*t*(1.f + erff(t*0.70710678118654752f));
    v[j] = ge; s += ge;
  }
#pragma unroll
  for (int off = 1; off < 64; off <<= 1) s += __shfl_xor(s, off);
  float mu = s * (1.f/D);
  float q = 0.f;
#pragma unroll
  for (int j = 0; j < CPL; j++){ float d = v[j]-mu; q += d*d; }
#pragma unroll
  for (int off = 1; off < 64; off <<= 1) q += __shfl_xor(q, off);
  float inv = 1.f / sqrtf(q*(1.f/D) + 1e-5f);
#pragma unroll
  for (int j = 0; j < CPL; j++){
    int c = lane*CPL + j;
    xr[j] = f2b(ldf(G, c, isw)*(v[j]-mu)*inv + ldf(Bt, c, isw));
  }
}

// ---- fused exact-GELU + LayerNorm, bf16 in -> f32 out --------------------
template<int CPL>
__global__ void gelu_ln_out(const bf16* __restrict__ X, const void* __restrict__ G,
                            const void* __restrict__ Bt, float* __restrict__ Out,
                            const int* __restrict__ wflag){
  int isw = wflag[0];
  int node = blockIdx.x*4 + (threadIdx.x >> 6);
  if (node >= NN) return;
  constexpr int D = CPL*64;
  int lane = threadIdx.x & 63;
  const bf16* xr = X + (size_t)node*D + lane*CPL;
  float v[CPL]; float s = 0.f;
#pragma unroll
  for (int j = 0; j < CPL; j++){
    float t = b2f(xr[j]);
    float ge = 0.5f*t*(1.f + erff(t*0.70710678118654752f));
    v[j] = ge; s += ge;
  }
#pragma unroll
  for (int off = 1; off < 64; off <<= 1) s += __shfl_xor(s, off);
  float mu = s * (1.f/D);
  float q = 0.f;
#pragma unroll
  for (int j = 0; j < CPL; j++){ float d = v[j]-mu; q += d*d; }
#pragma unroll
  for (int off = 1; off < 64; off <<= 1) q += __shfl_xor(q, off);
  float inv = 1.f / sqrtf(q*(1.f/D) + 1e-5f);
#pragma unroll
  for (int j = 0; j < CPL; j++){
    int c = lane*CPL + j;
    Out[(size_t)node*D + c] = ldf(G, c, isw)*(v[j]-mu)*inv + ldf(Bt, c, isw);
  }
}

// ---- tiny fc: out = h2 @ fc_W + fc_b -> f32 ------------------------------
__global__ void fc_k(const bf16* __restrict__ X, const void* __restrict__ W,
                     const void* __restrict__ B, float* __restrict__ Out,
                     int K, int D, const int* __restrict__ wflag){
  int isw = wflag[0];
  int m = blockIdx.x*4 + (threadIdx.x >> 6);
  int lane = threadIdx.x & 63;
  if (m >= NN || lane >= D) return;
  float acc = ldf(B, lane, isw);
  for (int k = 0; k < K; k++) acc += b2f(X[(size_t)m*K + k]) * ldf(W, (size_t)k*D + lane, isw);
  Out[(size_t)m*D + lane] = acc;
}

// ---- one attention tile (head group), bf16 activations -------------------
template<int CPL, int H>
static void run_tile(const void* Xin, const int* xflag, int Kdim, int Dfull, int col,
                     const void* Wq, const void* bq, const void* Wk, const void* bk,
                     const void* Wv, const void* bv, const void* Wsk, const void* bsk,
                     bf16* Qc, bf16* Kc, bf16* Xout, bf16* LOG, float* Mx, float* Dn,
                     const int* ei, const int* PERM, const int* OFFS, const int* WFLAG,
                     float* attn, float scale, hipStream_t stream){
  constexpr int Dt = CPL*64;
  dim3 gg(Dt/64, NN/4);
  gemm_bias<4><<<gg,64,0,stream>>>(Xin, Wq,  bq,  Qc,   Kdim, Dt, col, Dfull, 0,   Dt,    xflag, WFLAG);
  gemm_bias<4><<<gg,64,0,stream>>>(Xin, Wk,  bk,  Kc,   Kdim, Dt, col, Dfull, 0,   Dt,    xflag, WFLAG);
  gemm_bias<4><<<gg,64,0,stream>>>(Xin, Wsk, bsk, Xout, Kdim, Dt, col, Dfull, col, Dfull, xflag, WFLAG);
  edge_logits<CPL,H><<<NE/4, 256, 0, stream>>>(Qc, Kc, ei, PERM, LOG, scale);
  seg_maxsum<H><<<(NN*H+255)/256, 256, 0, stream>>>(LOG, OFFS, Mx, Dn);
  alpha_k<H><<<((size_t)NE*H+255)/256, 256, 0, stream>>>(LOG, Mx, Dn, ei, PERM, attn);
  gemm_bias<4><<<gg,64,0,stream>>>(Xin, Wv, bv, Qc, Kdim, Dt, col, Dfull, 0, Dt, xflag, WFLAG); // V -> Qc
  aggregate<CPL,H><<<(NN+3)/4, 256, 0, stream>>>(Qc, LOG, ei, PERM, OFFS, Xout, Dfull, col);
}

extern "C" void kernel_launch(void* const* d_in, const int* in_sizes, int n_in,
                              void* d_out, int out_size, void* d_ws, size_t ws_size,
                              hipStream_t stream){
  // ---------- input layout resolver (A confirmed by size-verification) ----
  int iX=-1, iEI=-1, iW[4][4], iB[4][4], iG[4], iBt[4], ifcW=-1, ifcB=-1;
  int code = 0;
  if (n_in != 44) code = 100;
  else if (in_sizes[0] == NN*128 && in_sizes[1] == 2*NE){
    iX = 0; iEI = 1;
    if (in_sizes[3] == 32768){           // A: grouped (dict order)
      for (int l = 0; l < 4; l++)
        for (int j = 0; j < 4; j++){ iW[l][j] = 2+l*8+j; iB[l][j] = 2+l*8+4+j; }
    } else {                              // B: interleaved (signature order)
      for (int l = 0; l < 4; l++)
        for (int j = 0; j < 4; j++){ iW[l][j] = 2+l*8+2*j; iB[l][j] = 2+l*8+2*j+1; }
    }
    for (int l = 0; l < 4; l++){ iG[l] = 34+2*l; iBt[l] = 35+2*l; }
    ifcW = 42; ifcB = 43;
  } else if (in_sizes[43] == NN*128){     // C: alphabetical
    iX = 43; iEI = 32; ifcW = 33; ifcB = 34;
    for (int l = 0; l < 4; l++){
      int base = l*8;
      iW[l][0] = base+1; iW[l][1] = base+0; iW[l][2] = base+3; iW[l][3] = base+2;
      iB[l][0] = base+5; iB[l][1] = base+4; iB[l][2] = base+7; iB[l][3] = base+6;
    }
    for (int l = 0; l < 4; l++){ iBt[l] = 35+2*l; iG[l] = 36+2*l; }
  } else code = 120;

  if (!code){
    const int wsz[4] = {32768,16384,16384,32768};
    const int bsz[4] = {256,64,256,128};
    bool ok = in_sizes[iX] == NN*128 && in_sizes[iEI] == 2*NE
           && in_sizes[ifcW] == 640 && in_sizes[ifcB] == 10;
    for (int l = 0; l < 4; l++){
      for (int j = 0; j < 4; j++)
        ok = ok && in_sizes[iW[l][j]] == wsz[l] && in_sizes[iB[l][j]] == bsz[l];
      ok = ok && in_sizes[iG[l]] == bsz[l] && in_sizes[iBt[l]] == bsz[l];
    }
    if (!ok) code = 140;
  }
  if (code){
    fill_k<<<((size_t)out_size+255)/256, 256, 0, stream>>>((float*)d_out, out_size, (float)code);
    return;
  }

  const void* x = d_in[iX];
  const int*  ei = (const int*)d_in[iEI];
  const void *W[4][4], *Bw[4][4], *lng[4], *lnb[4];
  for (int l = 0; l < 4; l++){
    for (int j = 0; j < 4; j++){ W[l][j] = d_in[iW[l][j]]; Bw[l][j] = d_in[iB[l][j]]; }
    lng[l] = d_in[iG[l]]; lnb[l] = d_in[iBt[l]];
  }
  const void* fcW = d_in[ifcW];
  const void* fcB = d_in[ifcB];

  char* ws = (char*)d_ws;
  size_t o = 0;
  auto alloc = [&](size_t bytes)->void*{ void* p = ws + o; o += (bytes + 255)/256*256; return p; };
  bf16* Hb   = (bf16*)alloc((size_t)NN*256*2);   // 10.24 MB
  bf16* H2b  = (bf16*)alloc((size_t)NN*64*2);    //  2.56 MB
  bf16* Qc   = (bf16*)alloc((size_t)NN*128*2);   //  5.12 MB
  bf16* Kc   = (bf16*)alloc((size_t)NN*128*2);   //  5.12 MB
  bf16* LOG  = (bf16*)alloc((size_t)NE*8*2);     //  5.12 MB
  float* Mx  = (float*)alloc((size_t)NN*8*4);
  float* Dn  = (float*)alloc((size_t)NN*8*4);
  int* OFFS  = (int*)alloc((size_t)(NN+1)*4);
  int* CURS  = (int*)alloc((size_t)(NN+1)*4);
  int* PERM  = (int*)alloc((size_t)NE*4);
  int* FLAG  = (int*)alloc(256);
  size_t need = o;                               // ~31 MB

  float* out_x  = (float*)d_out;                 // [NN,10]   f32
  float* out_h4 = out_x + (size_t)NN*10;         // [NN,128]  f32
  float* out_at = out_h4 + (size_t)NN*128;       // [NE,8]    f32

  if (ws_size < need){
    fill_k<<<((size_t)out_size+255)/256, 256, 0, stream>>>((float*)d_out, out_size, 160.0f);
    return;
  }

  detect_k<<<1, 64, 0, stream>>>((const ushort_t*)x, FLAG);
  const int* FLAGZ = FLAG + 1;   // ==0: internal bf16 buffers

  hipMemsetAsync(CURS, 0, (size_t)NN*4, stream);
  count_k<<<(NE+255)/256, 256, 0, stream>>>(ei, CURS, NE);
  exscan_k<<<1, 1024, 0, stream>>>(CURS, OFFS, NN);
  hipMemcpyAsync(CURS, OFFS, (size_t)NN*4, hipMemcpyDeviceToDevice, stream);
  scatter_k<<<(NE+255)/256, 256, 0, stream>>>(ei, CURS, PERM, NE);

  const float s32  = 1.0f/sqrtf(32.f);
  const float s8   = 1.0f/sqrtf(8.f);
  const float s128 = 1.0f/sqrtf(128.f);

  // L1: 128 -> 256, H=8 (two 4-head tiles of 128 cols); x read dual-dtype
  run_tile<2,4>(x, FLAG, 128, 256,   0, W[0][0],Bw[0][0], W[0][1],Bw[0][1], W[0][2],Bw[0][2], W[0][3],Bw[0][3],
                Qc,Kc,Hb,LOG,Mx,Dn, ei,PERM,OFFS,FLAG, nullptr, s32, stream);
  run_tile<2,4>(x, FLAG, 128, 256, 128, W[0][0],Bw[0][0], W[0][1],Bw[0][1], W[0][2],Bw[0][2], W[0][3],Bw[0][3],
                Qc,Kc,Hb,LOG,Mx,Dn, ei,PERM,OFFS,FLAG, nullptr, s32, stream);
  gelu_ln_ip<4><<<(NN+3)/4,256,0,stream>>>(Hb, lng[0], lnb[0], FLAG);

  // L2: 256 -> 64, H=8 (emits attn as f32)
  run_tile<1,8>(Hb, FLAGZ, 256, 64, 0, W[1][0],Bw[1][0], W[1][1],Bw[1][1], W[1][2],Bw[1][2], W[1][3],Bw[1][3],
                Qc,Kc,H2b,LOG,Mx,Dn, ei,PERM,OFFS,FLAG, out_at, s8, stream);
  gelu_ln_ip<1><<<(NN+3)/4,256,0,stream>>>(H2b, lng[1], lnb[1], FLAG);

  // L3: 64 -> 256, H=8 (two 4-head tiles)
  run_tile<2,4>(H2b, FLAGZ, 64, 256,   0, W[2][0],Bw[2][0], W[2][1],Bw[2][1], W[2][2],Bw[2][2], W[2][3],Bw[2][3],
                Qc,Kc,Hb,LOG,Mx,Dn, ei,PERM,OFFS,FLAG, nullptr, s32, stream);
  run_tile<2,4>(H2b, FLAGZ, 64, 256, 128, W[2][0],Bw[2][0], W[2][1],Bw[2][1], W[2][2],Bw[2][2], W[2][3],Bw[2][3],
                Qc,Kc,Hb,LOG,Mx,Dn, ei,PERM,OFFS,FLAG, nullptr, s32, stream);
  gelu_ln_ip<4><<<(NN+3)/4,256,0,stream>>>(Hb, lng[2], lnb[2], FLAG);

  // L4: 256 -> 128, H=1. Skip-gemm reordered AFTER edge_logits so Kc can be
  // reused as the output tile; final GELU+LN writes f32 out_h4.
  {
    dim3 gg(2, NN/4);
    gemm_bias<4><<<gg,64,0,stream>>>(Hb, W[3][0], Bw[3][0], Qc, 256, 128, 0, 128, 0, 128, FLAGZ, FLAG);
    gemm_bias<4><<<gg,64,0,stream>>>(Hb, W[3][1], Bw[3][1], Kc, 256, 128, 0, 128, 0, 128, FLAGZ, FLAG);
    edge_logits<2,1><<<NE/4, 256, 0, stream>>>(Qc, Kc, ei, PERM, LOG, s128);
    seg_maxsum<1><<<(NN+255)/256, 256, 0, stream>>>(LOG, OFFS, Mx, Dn);
    alpha_k<1><<<(NE+255)/256, 256, 0, stream>>>(LOG, Mx, Dn, ei, PERM, nullptr);
    gemm_bias<4><<<gg,64,0,stream>>>(Hb, W[3][3], Bw[3][3], Kc, 256, 128, 0, 128, 0, 128, FLAGZ, FLAG); // skip -> Kc
    gemm_bias<4><<<gg,64,0,stream>>>(Hb, W[3][2], Bw[3][2], Qc, 256, 128, 0, 128, 0, 128, FLAGZ, FLAG); // V -> Qc
    aggregate<2,1><<<(NN+3)/4, 256, 0, stream>>>(Qc, LOG, ei, PERM, OFFS, Kc, 128, 0);
    gelu_ln_out<2><<<(NN+3)/4,256,0,stream>>>(Kc, lng[3], lnb[3], out_h4, FLAG);
  }

  // fc on h2 -> f32 out
  fc_k<<<(NN+3)/4, 256, 0, stream>>>(H2b, fcW, fcB, out_x, 64, 10, FLAG);
}

// Round 7
// 1561.813 us; speedup vs baseline: 3.3257x; 3.3257x over previous
//
#include <hip/hip_runtime.h>
#include <hip/hip_bf16.h>
#include <math.h>

#define NN 20000
#define NE 320000

typedef __hip_bfloat16 bf16;

__device__ __forceinline__ float b2f(bf16 v){ return __bfloat162float(v); }
__device__ __forceinline__ bf16 f2b(float v){ return __float2bfloat16(v); }
__device__ __forceinline__ int clampi(int v, int lo, int hi){ return v < lo ? lo : (v > hi ? hi : v); }

struct b4{ bf16 x,y,z,w; };

__device__ __forceinline__ void ldx4(const float* p, float&a,float&b,float&c,float&d){
  float4 v = *reinterpret_cast<const float4*>(p); a=v.x; b=v.y; c=v.z; d=v.w;
}
__device__ __forceinline__ void ldx4(const bf16* p, float&a,float&b,float&c,float&d){
  b4 v = *reinterpret_cast<const b4*>(p); a=b2f(v.x); b=b2f(v.y); c=b2f(v.z); d=b2f(v.w);
}
__device__ __forceinline__ void stv(bf16* p, float v){ *p = f2b(v); }
__device__ __forceinline__ void stv(float* p, float v){ *p = v; }
__device__ __forceinline__ float ldv(const bf16* p){ return b2f(*p); }
__device__ __forceinline__ float ldv(const float* p){ return *p; }

// ---- diagnostic fill (f32 out) -------------------------------------------
__global__ void fill_k(float* __restrict__ out, int n, float val){
  int i = blockIdx.x*blockDim.x + threadIdx.x;
  if (i < n) out[i] = val;
}

// ---- CSR build -----------------------------------------------------------
__global__ void count_k(const int* __restrict__ ei, int* __restrict__ cnt, int E){
  int e = blockIdx.x*blockDim.x + threadIdx.x;
  if (e < E){
    int d = clampi(ei[E + e], 0, NN-1);
    atomicAdd(&cnt[d], 1);
  }
}

__global__ void exscan_k(const int* __restrict__ cnt, int* __restrict__ off, int n){
  __shared__ int wtot[16];
  __shared__ int carrysh;
  int tid = threadIdx.x, lane = tid & 63, w = tid >> 6;
  if (tid == 0) carrysh = 0;
  __syncthreads();
  for (int base = 0; base < n; base += 1024){
    int i = base + tid;
    int v = (i < n) ? cnt[i] : 0;
    int s = v;
#pragma unroll
    for (int d = 1; d < 64; d <<= 1){
      int t = __shfl_up(s, d);
      if (lane >= d) s += t;
    }
    if (lane == 63) wtot[w] = s;
    __syncthreads();
    int woff = 0;
    for (int j = 0; j < w; j++) woff += wtot[j];
    int c = carrysh;
    if (i < n) off[i] = c + woff + s - v;   // exclusive prefix
    __syncthreads();
    if (tid == 1023) carrysh = c + woff + s;
    __syncthreads();
  }
  if (threadIdx.x == 0) off[n] = carrysh;
}

__global__ void scatter_k(const int* __restrict__ ei, int* __restrict__ cur,
                          int* __restrict__ perm, int E){
  int e = blockIdx.x*blockDim.x + threadIdx.x;
  if (e >= E) return;
  int d = clampi(ei[E + e], 0, NN-1);
  int p = atomicAdd(&cur[d], 1);
  if (p >= 0 && p < E) perm[p] = e;
}

// ---- GEMM: Out[m, ocol+n] = sum_k X[m,k]*W[k, wcol+n] + B[wcol+n] --------
// 64 threads along n, 8 rows/block, k unrolled x4, vector X loads.
template<typename XT, typename TO>
__global__ void gemm_bias(const XT* __restrict__ X, const float* __restrict__ W,
                          const float* __restrict__ Bb, TO* __restrict__ Out,
                          int K, int wcol, int ldW, int ocol, int ldO){
  int n = blockIdx.x*64 + threadIdx.x;
  size_t m0 = (size_t)blockIdx.y * 8;
  float bias = Bb[wcol + n];
  float acc[8];
#pragma unroll
  for (int r = 0; r < 8; r++) acc[r] = bias;
  const float* wp = W + wcol + n;
  for (int k = 0; k < K; k += 4){
    float w0 = wp[(size_t)(k+0)*ldW];
    float w1 = wp[(size_t)(k+1)*ldW];
    float w2 = wp[(size_t)(k+2)*ldW];
    float w3 = wp[(size_t)(k+3)*ldW];
#pragma unroll
    for (int r = 0; r < 8; r++){
      float x0,x1,x2,x3;
      ldx4(X + (m0+r)*K + k, x0,x1,x2,x3);
      acc[r] += x0*w0 + x1*w1 + x2*w2 + x3*w3;
    }
  }
#pragma unroll
  for (int r = 0; r < 8; r++) stv(&Out[(m0+r)*(size_t)ldO + ocol + n], acc[r]);
}

// ---- fused per-node attention: logits + online softmax + aggregate -------
// One wave per dst node. Q row in registers; per edge gather K/V rows.
// Optionally stores logits (LOG, CSR order) + final max/denom for alpha out.
template<int D, int H, typename TO>
__global__ void fused_attn(const bf16* __restrict__ Q, const bf16* __restrict__ Kf,
                           const bf16* __restrict__ V, const int* __restrict__ ei,
                           const int* __restrict__ perm, const int* __restrict__ offs,
                           TO* __restrict__ Xout, int ldO, int col0,
                           bf16* __restrict__ LOG, float* __restrict__ MxO,
                           float* __restrict__ DnO, float scale){
  constexpr int CPL = D/64;
  constexpr int LPH = 64/H;
  int node = blockIdx.x*4 + (threadIdx.x >> 6);
  if (node >= NN) return;
  int lane = threadIdx.x & 63;
  float q[CPL];
  const bf16* qr = Q + (size_t)node*D + lane*CPL;
#pragma unroll
  for (int j = 0; j < CPL; j++) q[j] = b2f(qr[j]) * scale;
  float m = -INFINITY, den = 0.f;
  float acc[CPL];
#pragma unroll
  for (int j = 0; j < CPL; j++) acc[j] = 0.f;
  int s0 = offs[node], e0 = offs[node+1];
  for (int i = s0; i < e0; i++){
    int e = perm[i];
    int s = ei[e];
    const bf16* kr = Kf + (size_t)s*D + lane*CPL;
    const bf16* vr = V  + (size_t)s*D + lane*CPL;
    float kv[CPL], vv[CPL];
#pragma unroll
    for (int j = 0; j < CPL; j++){ kv[j] = b2f(kr[j]); vv[j] = b2f(vr[j]); }
    float t = 0.f;
#pragma unroll
    for (int j = 0; j < CPL; j++) t += q[j]*kv[j];
#pragma unroll
    for (int o = 1; o < LPH; o <<= 1) t += __shfl_xor(t, o);
    if (LOG && (lane & (LPH-1)) == 0) LOG[(size_t)i*H + lane/LPH] = f2b(t);
    float nm = fmaxf(m, t);
    float fe = __expf(m - nm);    // 0 when m==-inf
    float pe = __expf(t - nm);
    den = den*fe + pe;
#pragma unroll
    for (int j = 0; j < CPL; j++) acc[j] = acc[j]*fe + pe*vv[j];
    m = nm;
  }
  float inv = 1.f/(den + 1e-16f);
  TO* o = Xout + (size_t)node*ldO + col0 + lane*CPL;
#pragma unroll
  for (int j = 0; j < CPL; j++) stv(&o[j], ldv(&o[j]) + acc[j]*inv);
  if (MxO && (lane & (LPH-1)) == 0){
    MxO[node*H + lane/LPH] = m;
    DnO[node*H + lane/LPH] = den;
  }
}

// ---- alpha scatter for L2 (attn output, original edge order, f32) --------
__global__ void alpha8_k(const bf16* __restrict__ LOG, const float* __restrict__ Mx,
                         const float* __restrict__ Dn, const int* __restrict__ ei,
                         const int* __restrict__ perm, float* __restrict__ attn){
  size_t t = (size_t)blockIdx.x*blockDim.x + threadIdx.x;
  if (t >= (size_t)NE*8) return;
  int pos = (int)(t >> 3), h = (int)(t & 7);
  int e = perm[pos];
  int node = ei[NE + e];
  float a = __expf(b2f(LOG[t]) - Mx[node*8 + h]) / (Dn[node*8 + h] + 1e-16f);
  attn[(size_t)e*8 + h] = a;
}

// ---- fused exact-GELU + LayerNorm, in place ------------------------------
template<int CPL, typename T>
__global__ void gelu_ln(T* __restrict__ X, const float* __restrict__ G,
                        const float* __restrict__ Bt){
  int node = blockIdx.x*4 + (threadIdx.x >> 6);
  if (node >= NN) return;
  constexpr int D = CPL*64;
  int lane = threadIdx.x & 63;
  T* xr = X + (size_t)node*D + lane*CPL;
  float v[CPL]; float s = 0.f;
#pragma unroll
  for (int j = 0; j < CPL; j++){
    float t = ldv(&xr[j]);
    float ge = 0.5f*t*(1.f + erff(t*0.70710678118654752f));
    v[j] = ge; s += ge;
  }
#pragma unroll
  for (int off = 1; off < 64; off <<= 1) s += __shfl_xor(s, off);
  float mu = s * (1.f/D);
  float q = 0.f;
#pragma unroll
  for (int j = 0; j < CPL; j++){ float d = v[j]-mu; q += d*d; }
#pragma unroll
  for (int off = 1; off < 64; off <<= 1) q += __shfl_xor(q, off);
  float inv = 1.f / sqrtf(q*(1.f/D) + 1e-5f);
#pragma unroll
  for (int j = 0; j < CPL; j++){
    int c = lane*CPL + j;
    stv(&xr[j], G[c]*(v[j]-mu)*inv + Bt[c]);
  }
}

// ---- tiny fc: out = h2 @ fc_W + fc_b -> f32 ------------------------------
__global__ void fc_k(const bf16* __restrict__ X, const float* __restrict__ W,
                     const float* __restrict__ B, float* __restrict__ Out,
                     int K, int D){
  int m = blockIdx.x*4 + (threadIdx.x >> 6);
  int lane = threadIdx.x & 63;
  if (m >= NN || lane >= D) return;
  float acc = B[lane];
  for (int k = 0; k < K; k++) acc += b2f(X[(size_t)m*K + k]) * W[(size_t)k*D + lane];
  Out[(size_t)m*D + lane] = acc;
}

extern "C" void kernel_launch(void* const* d_in, const int* in_sizes, int n_in,
                              void* d_out, int out_size, void* d_ws, size_t ws_size,
                              hipStream_t stream){
  // layout A (dict order) — verified in round 6; keep size checks as insurance
  int code = 0;
  if (n_in != 44) code = 100;
  else {
    const int wsz[4] = {32768,16384,16384,32768};
    const int bsz[4] = {256,64,256,128};
    bool ok = in_sizes[0] == NN*128 && in_sizes[1] == 2*NE
           && in_sizes[42] == 640 && in_sizes[43] == 10;
    for (int l = 0; l < 4 && ok; l++){
      for (int j = 0; j < 4; j++)
        ok = ok && in_sizes[2+l*8+j] == wsz[l] && in_sizes[2+l*8+4+j] == bsz[l];
      ok = ok && in_sizes[34+2*l] == bsz[l] && in_sizes[35+2*l] == bsz[l];
    }
    if (!ok) code = 140;
  }
  if (code){
    fill_k<<<((size_t)out_size+255)/256, 256, 0, stream>>>((float*)d_out, out_size, (float)code);
    return;
  }

  const float* x = (const float*)d_in[0];
  const int*   ei = (const int*)d_in[1];
  const float *W[4][4], *Bw[4][4], *lng[4], *lnb[4];
  for (int l = 0; l < 4; l++){
    for (int j = 0; j < 4; j++){
      W[l][j]  = (const float*)d_in[2 + l*8 + j];      // Wq,Wk,Wv,Ws
      Bw[l][j] = (const float*)d_in[2 + l*8 + 4 + j];  // bq,bk,bv,bs
    }
    lng[l] = (const float*)d_in[34 + 2*l];
    lnb[l] = (const float*)d_in[35 + 2*l];
  }
  const float* fcW = (const float*)d_in[42];
  const float* fcB = (const float*)d_in[43];

  // ---- workspace layout (explicit, ~29.5 MB; 30.9 MB proven available) ---
  char* ws = (char*)d_ws;
  size_t o = 0;
  auto alloc = [&](size_t bytes)->void*{ void* p = ws + o; o += (bytes + 255)/256*256; return p; };
  bf16* Hb   = (bf16*)alloc((size_t)NN*256*2);   // 10.24 MB activations
  bf16* H2b  = (bf16*)alloc((size_t)NN*64*2);    //  2.56 MB h2 (kept for fc)
  int* OFFS  = (int*)alloc((size_t)(NN+1)*4);
  int* PERM  = (int*)alloc((size_t)NE*4);
  char* AR   = (char*)alloc((size_t)3*NN*128*2); // 15.36 MB arena
  size_t need = o;
  // arena views
  bf16* Qc = (bf16*)AR;                          // tile Q (D<=128)
  bf16* Kc = (bf16*)(AR + (size_t)NN*128*2);
  bf16* Vc = (bf16*)(AR + (size_t)2*NN*128*2);
  int*  CURS = (int*)AR;                         // setup only
  // L2 compact overlay (D=64)
  bf16* q2  = (bf16*)AR;
  bf16* k2  = (bf16*)(AR + 2560000);
  bf16* v2  = (bf16*)(AR + 5120000);
  bf16* LOG = (bf16*)(AR + 7680000);             // NE*8 bf16 = 5.12 MB
  float* Mx = (float*)(AR + 12800000);           // NN*8 f32
  float* Dn = (float*)(AR + 13440000);

  float* out_x  = (float*)d_out;                 // [NN,10]
  float* out_h4 = out_x + (size_t)NN*10;         // [NN,128]
  float* out_at = out_h4 + (size_t)NN*128;       // [NE,8]

  if (ws_size < need){
    fill_k<<<((size_t)out_size+255)/256, 256, 0, stream>>>((float*)d_out, out_size, 160.0f);
    return;
  }

  // ---- CSR by dst ----
  hipMemsetAsync(CURS, 0, (size_t)NN*4, stream);
  count_k<<<NE/256, 256, 0, stream>>>(ei, CURS, NE);
  exscan_k<<<1, 1024, 0, stream>>>(CURS, OFFS, NN);
  hipMemcpyAsync(CURS, OFFS, (size_t)NN*4, hipMemcpyDeviceToDevice, stream);
  scatter_k<<<NE/256, 256, 0, stream>>>(ei, CURS, PERM, NE);

  const float s32  = 0.1767766952966369f;   // 1/sqrt(32)
  const float s8   = 0.3535533905932738f;   // 1/sqrt(8)
  const float s128 = 0.0883883476483184f;   // 1/sqrt(128)
  const dim3 g64(1, NN/8), g128(2, NN/8);

  // ---- L1: 128 -> 256, H=8 (two 4-head tiles of 128 cols), X = x (f32) ---
  for (int col = 0; col <= 128; col += 128){
    gemm_bias<float,bf16><<<g128,64,0,stream>>>(x, W[0][0], Bw[0][0], Qc, 128, col, 256, 0, 128);
    gemm_bias<float,bf16><<<g128,64,0,stream>>>(x, W[0][1], Bw[0][1], Kc, 128, col, 256, 0, 128);
    gemm_bias<float,bf16><<<g128,64,0,stream>>>(x, W[0][2], Bw[0][2], Vc, 128, col, 256, 0, 128);
    gemm_bias<float,bf16><<<g128,64,0,stream>>>(x, W[0][3], Bw[0][3], Hb, 128, col, 256, col, 256);
    fused_attn<128,4,bf16><<<NN/4,256,0,stream>>>(Qc,Kc,Vc, ei,PERM,OFFS, Hb,256,col,
                                                  nullptr,nullptr,nullptr, s32);
  }
  gelu_ln<4><<<NN/4,256,0,stream>>>(Hb, lng[0], lnb[0]);

  // ---- L2: 256 -> 64, H=8 (emits attn) -----------------------------------
  gemm_bias<bf16,bf16><<<g64,64,0,stream>>>(Hb, W[1][0], Bw[1][0], q2, 256, 0, 64, 0, 64);
  gemm_bias<bf16,bf16><<<g64,64,0,stream>>>(Hb, W[1][1], Bw[1][1], k2, 256, 0, 64, 0, 64);
  gemm_bias<bf16,bf16><<<g64,64,0,stream>>>(Hb, W[1][2], Bw[1][2], v2, 256, 0, 64, 0, 64);
  gemm_bias<bf16,bf16><<<g64,64,0,stream>>>(Hb, W[1][3], Bw[1][3], H2b, 256, 0, 64, 0, 64);
  fused_attn<64,8,bf16><<<NN/4,256,0,stream>>>(q2,k2,v2, ei,PERM,OFFS, H2b,64,0,
                                               LOG,Mx,Dn, s8);
  alpha8_k<<<NE*8/256,256,0,stream>>>(LOG, Mx, Dn, ei, PERM, out_at);
  gelu_ln<1><<<NN/4,256,0,stream>>>(H2b, lng[1], lnb[1]);

  // fc on h2 (independent of L3/L4)
  fc_k<<<NN/4,256,0,stream>>>(H2b, fcW, fcB, out_x, 64, 10);

  // ---- L3: 64 -> 256, H=8 (two 4-head tiles), X = H2b --------------------
  for (int col = 0; col <= 128; col += 128){
    gemm_bias<bf16,bf16><<<g128,64,0,stream>>>(H2b, W[2][0], Bw[2][0], Qc, 64, col, 256, 0, 128);
    gemm_bias<bf16,bf16><<<g128,64,0,stream>>>(H2b, W[2][1], Bw[2][1], Kc, 64, col, 256, 0, 128);
    gemm_bias<bf16,bf16><<<g128,64,0,stream>>>(H2b, W[2][2], Bw[2][2], Vc, 64, col, 256, 0, 128);
    gemm_bias<bf16,bf16><<<g128,64,0,stream>>>(H2b, W[2][3], Bw[2][3], Hb, 64, col, 256, col, 256);
    fused_attn<128,4,bf16><<<NN/4,256,0,stream>>>(Qc,Kc,Vc, ei,PERM,OFFS, Hb,256,col,
                                                  nullptr,nullptr,nullptr, s32);
  }
  gelu_ln<4><<<NN/4,256,0,stream>>>(Hb, lng[2], lnb[2]);

  // ---- L4: 256 -> 128, H=1; skip+agg accumulate f32 in out_h4 ------------
  gemm_bias<bf16,bf16><<<g128,64,0,stream>>>(Hb, W[3][0], Bw[3][0], Qc, 256, 0, 128, 0, 128);
  gemm_bias<bf16,bf16><<<g128,64,0,stream>>>(Hb, W[3][1], Bw[3][1], Kc, 256, 0, 128, 0, 128);
  gemm_bias<bf16,bf16><<<g128,64,0,stream>>>(Hb, W[3][2], Bw[3][2], Vc, 256, 0, 128, 0, 128);
  gemm_bias<bf16,float><<<g128,64,0,stream>>>(Hb, W[3][3], Bw[3][3], out_h4, 256, 0, 128, 0, 128);
  fused_attn<128,1,float><<<NN/4,256,0,stream>>>(Qc,Kc,Vc, ei,PERM,OFFS, out_h4,128,0,
                                                 nullptr,nullptr,nullptr, s128);
  gelu_ln<2><<<NN/4,256,0,stream>>>(out_h4, lng[3], lnb[3]);
}

// Round 8
// 763.088 us; speedup vs baseline: 6.8068x; 2.0467x over previous
//
#include <hip/hip_runtime.h>
#include <hip/hip_bf16.h>
#include <math.h>

#define NN 20000
#define MP 20032            // NN padded to 64 (MFMA row tiles)
#define NE 320000

typedef __hip_bfloat16 bf16;
typedef __attribute__((ext_vector_type(8))) short short8v;   // 8 bf16 (4 VGPR)
typedef __attribute__((ext_vector_type(4))) float f32x4;

__device__ __forceinline__ float b2f(bf16 v){ return __bfloat162float(v); }
__device__ __forceinline__ bf16 f2b(float v){ return __float2bfloat16(v); }
__device__ __forceinline__ int clampi(int v, int lo, int hi){ return v < lo ? lo : (v > hi ? hi : v); }
__device__ __forceinline__ void stv(bf16* p, float v){ *p = f2b(v); }
__device__ __forceinline__ void stv(float* p, float v){ *p = v; }
__device__ __forceinline__ float ldv(const bf16* p){ return b2f(*p); }
__device__ __forceinline__ float ldv(const float* p){ return *p; }

// ---- diagnostic fill ------------------------------------------------------
__global__ void fill_k(float* __restrict__ out, int n, float val){
  int i = blockIdx.x*blockDim.x + threadIdx.x;
  if (i < n) out[i] = val;
}

// ---- x (f32, NN rows) -> bf16 padded (MP rows) ----------------------------
__global__ void cvtx_k(const float* __restrict__ x, bf16* __restrict__ out){
  int i = blockIdx.x*256 + threadIdx.x;          // over MP*128
  if (i >= MP*128) return;
  int row = i >> 7;
  out[i] = f2b(row < NN ? x[i] : 0.f);
}

// ---- weight pack: W [K x D] f32 -> MFMA B-fragment order bf16 --------------
// idx = ((s*TG + tg)*64 + lane)*8 + j ; k = s*32 + (lane>>4)*8 + j ; n = tg*16 + (lane&15)
__global__ void pack_w(const float* __restrict__ W, bf16* __restrict__ Wp, int K, int D){
  int i = blockIdx.x*256 + threadIdx.x;
  if (i >= K*D) return;
  int j = i & 7, l = (i >> 3) & 63;
  int TG = D >> 4;
  int tg = (i >> 9) % TG, s = (i >> 9) / TG;
  int k = s*32 + (l >> 4)*8 + j, n = tg*16 + (l & 15);
  Wp[i] = f2b(W[(size_t)k*D + n]);
}

// ---- MFMA GEMM: Out[m, ocol+c] = sum_k X[m,k]*W[k,c] + bias[c] -------------
// 256 thr = 4 waves; 64x64 tile/block; wave w does rows m0+16w..+15, 4 n-tiles.
template<typename TO>
__global__ void gemm_mfma(const bf16* __restrict__ X, const short8v* __restrict__ Wp,
                          const float* __restrict__ Bb, TO* __restrict__ Out,
                          int K, int TG, int tg0, int ldO, int ocol, int Mstore){
  int w = threadIdx.x >> 6, lane = threadIdx.x & 63;
  int n0 = blockIdx.x*64;
  size_t m0 = (size_t)blockIdx.y*64 + w*16;
  int lr = lane & 15, lk = lane >> 4;
  const bf16* xp = X + (m0 + lr)*K + lk*8;
  const short8v* wp = Wp + ((size_t)(tg0 + (n0 >> 4)))*64 + lane;
  f32x4 acc[4] = {f32x4{0,0,0,0},f32x4{0,0,0,0},f32x4{0,0,0,0},f32x4{0,0,0,0}};
  int steps = K >> 5;
  for (int s = 0; s < steps; s++){
    short8v a = *reinterpret_cast<const short8v*>(xp + s*32);
    const short8v* wrow = wp + (size_t)s*TG*64;
#pragma unroll
    for (int t = 0; t < 4; t++){
      short8v b = wrow[t*64];
      acc[t] = __builtin_amdgcn_mfma_f32_16x16x32_bf16(a, b, acc[t], 0, 0, 0);
    }
  }
#pragma unroll
  for (int t = 0; t < 4; t++){
    int col = n0 + t*16 + lr;
    float bias = Bb[col];
#pragma unroll
    for (int r = 0; r < 4; r++){
      int row = (int)m0 + lk*4 + r;
      if (row < Mstore) stv(&Out[(size_t)row*ldO + ocol + col], acc[t][r] + bias);
    }
  }
}

// ---- CSR build -------------------------------------------------------------
__global__ void count_k(const int* __restrict__ ei, int* __restrict__ cnt, int E){
  int e = blockIdx.x*blockDim.x + threadIdx.x;
  if (e < E){
    int d = clampi(ei[E + e], 0, NN-1);
    atomicAdd(&cnt[d], 1);
  }
}

__global__ void exscan_k(const int* __restrict__ cnt, int* __restrict__ off, int n){
  __shared__ int wtot[16];
  __shared__ int carrysh;
  int tid = threadIdx.x, lane = tid & 63, w = tid >> 6;
  if (tid == 0) carrysh = 0;
  __syncthreads();
  for (int base = 0; base < n; base += 1024){
    int i = base + tid;
    int v = (i < n) ? cnt[i] : 0;
    int s = v;
#pragma unroll
    for (int d = 1; d < 64; d <<= 1){
      int t = __shfl_up(s, d);
      if (lane >= d) s += t;
    }
    if (lane == 63) wtot[w] = s;
    __syncthreads();
    int woff = 0;
    for (int j = 0; j < w; j++) woff += wtot[j];
    int c = carrysh;
    if (i < n) off[i] = c + woff + s - v;
    __syncthreads();
    if (tid == 1023) carrysh = c + woff + s;
    __syncthreads();
  }
  if (threadIdx.x == 0) off[n] = carrysh;
}

__global__ void scatter_k(const int* __restrict__ ei, int* __restrict__ cur,
                          int* __restrict__ perm, int E){
  int e = blockIdx.x*blockDim.x + threadIdx.x;
  if (e >= E) return;
  int d = clampi(ei[E + e], 0, NN-1);
  int p = atomicAdd(&cur[d], 1);
  if (p >= 0 && p < E) perm[p] = e;
}

// ---- fused per-node attention (online softmax + aggregate) -----------------
template<int D, int H, typename TO>
__global__ void fused_attn(const bf16* __restrict__ Q, const bf16* __restrict__ Kf,
                           const bf16* __restrict__ V, const int* __restrict__ ei,
                           const int* __restrict__ perm, const int* __restrict__ offs,
                           TO* __restrict__ Xout, int ldO, int col0,
                           bf16* __restrict__ LOG, float* __restrict__ MxO,
                           float* __restrict__ DnO, float scale){
  constexpr int CPL = D/64;
  constexpr int LPH = 64/H;
  int node = blockIdx.x*4 + (threadIdx.x >> 6);
  if (node >= NN) return;
  int lane = threadIdx.x & 63;
  float q[CPL];
  const bf16* qr = Q + (size_t)node*D + lane*CPL;
#pragma unroll
  for (int j = 0; j < CPL; j++) q[j] = b2f(qr[j]) * scale;
  float m = -INFINITY, den = 0.f;
  float acc[CPL];
#pragma unroll
  for (int j = 0; j < CPL; j++) acc[j] = 0.f;
  int s0 = offs[node], e0 = offs[node+1];
  for (int i = s0; i < e0; i++){
    int e = perm[i];
    int s = ei[e];
    const bf16* kr = Kf + (size_t)s*D + lane*CPL;
    const bf16* vr = V  + (size_t)s*D + lane*CPL;
    float kv[CPL], vv[CPL];
#pragma unroll
    for (int j = 0; j < CPL; j++){ kv[j] = b2f(kr[j]); vv[j] = b2f(vr[j]); }
    float t = 0.f;
#pragma unroll
    for (int j = 0; j < CPL; j++) t += q[j]*kv[j];
#pragma unroll
    for (int o = 1; o < LPH; o <<= 1) t += __shfl_xor(t, o);
    if (LOG && (lane & (LPH-1)) == 0) LOG[(size_t)i*H + lane/LPH] = f2b(t);
    float nm = fmaxf(m, t);
    float fe = __expf(m - nm);
    float pe = __expf(t - nm);
    den = den*fe + pe;
#pragma unroll
    for (int j = 0; j < CPL; j++) acc[j] = acc[j]*fe + pe*vv[j];
    m = nm;
  }
  float inv = 1.f/(den + 1e-16f);
  TO* o = Xout + (size_t)node*ldO + col0 + lane*CPL;
#pragma unroll
  for (int j = 0; j < CPL; j++) stv(&o[j], ldv(&o[j]) + acc[j]*inv);
  if (MxO && (lane & (LPH-1)) == 0){
    MxO[node*H + lane/LPH] = m;
    DnO[node*H + lane/LPH] = den;
  }
}

// ---- alpha scatter for L2 --------------------------------------------------
__global__ void alpha8_k(const bf16* __restrict__ LOG, const float* __restrict__ Mx,
                         const float* __restrict__ Dn, const int* __restrict__ ei,
                         const int* __restrict__ perm, float* __restrict__ attn){
  size_t t = (size_t)blockIdx.x*blockDim.x + threadIdx.x;
  if (t >= (size_t)NE*8) return;
  int pos = (int)(t >> 3), h = (int)(t & 7);
  int e = perm[pos];
  int node = ei[NE + e];
  float a = __expf(b2f(LOG[t]) - Mx[node*8 + h]) / (Dn[node*8 + h] + 1e-16f);
  attn[(size_t)e*8 + h] = a;
}

// ---- fused exact-GELU + LayerNorm, in place --------------------------------
template<int CPL, typename T>
__global__ void gelu_ln(T* __restrict__ X, const float* __restrict__ G,
                        const float* __restrict__ Bt){
  int node = blockIdx.x*4 + (threadIdx.x >> 6);
  if (node >= NN) return;
  constexpr int D = CPL*64;
  int lane = threadIdx.x & 63;
  T* xr = X + (size_t)node*D + lane*CPL;
  float v[CPL]; float s = 0.f;
#pragma unroll
  for (int j = 0; j < CPL; j++){
    float t = ldv(&xr[j]);
    float ge = 0.5f*t*(1.f + erff(t*0.70710678118654752f));
    v[j] = ge; s += ge;
  }
#pragma unroll
  for (int off = 1; off < 64; off <<= 1) s += __shfl_xor(s, off);
  float mu = s * (1.f/D);
  float q = 0.f;
#pragma unroll
  for (int j = 0; j < CPL; j++){ float d = v[j]-mu; q += d*d; }
#pragma unroll
  for (int off = 1; off < 64; off <<= 1) q += __shfl_xor(q, off);
  float inv = 1.f / sqrtf(q*(1.f/D) + 1e-5f);
#pragma unroll
  for (int j = 0; j < CPL; j++){
    int c = lane*CPL + j;
    stv(&xr[j], G[c]*(v[j]-mu)*inv + Bt[c]);
  }
}

// ---- tiny fc ----------------------------------------------------------------
__global__ void fc_k(const bf16* __restrict__ X, const float* __restrict__ W,
                     const float* __restrict__ B, float* __restrict__ Out,
                     int K, int D){
  int m = blockIdx.x*4 + (threadIdx.x >> 6);
  int lane = threadIdx.x & 63;
  if (m >= NN || lane >= D) return;
  float acc = B[lane];
  for (int k = 0; k < K; k++) acc += b2f(X[(size_t)m*K + k]) * W[(size_t)k*D + lane];
  Out[(size_t)m*D + lane] = acc;
}

extern "C" void kernel_launch(void* const* d_in, const int* in_sizes, int n_in,
                              void* d_out, int out_size, void* d_ws, size_t ws_size,
                              hipStream_t stream){
  int code = 0;
  if (n_in != 44) code = 100;
  else {
    const int wsz[4] = {32768,16384,16384,32768};
    const int bsz[4] = {256,64,256,128};
    bool ok = in_sizes[0] == NN*128 && in_sizes[1] == 2*NE
           && in_sizes[42] == 640 && in_sizes[43] == 10;
    for (int l = 0; l < 4 && ok; l++){
      for (int j = 0; j < 4; j++)
        ok = ok && in_sizes[2+l*8+j] == wsz[l] && in_sizes[2+l*8+4+j] == bsz[l];
      ok = ok && in_sizes[34+2*l] == bsz[l] && in_sizes[35+2*l] == bsz[l];
    }
    if (!ok) code = 140;
  }
  if (code){
    fill_k<<<((size_t)out_size+255)/256, 256, 0, stream>>>((float*)d_out, out_size, (float)code);
    return;
  }

  const float* x = (const float*)d_in[0];
  const int*   ei = (const int*)d_in[1];
  const float *W[4][4], *Bw[4][4], *lng[4], *lnb[4];
  for (int l = 0; l < 4; l++){
    for (int j = 0; j < 4; j++){
      W[l][j]  = (const float*)d_in[2 + l*8 + j];      // Wq,Wk,Wv,Ws
      Bw[l][j] = (const float*)d_in[2 + l*8 + 4 + j];  // bq,bk,bv,bs
    }
    lng[l] = (const float*)d_in[34 + 2*l];
    lnb[l] = (const float*)d_in[35 + 2*l];
  }
  const float* fcW = (const float*)d_in[42];
  const float* fcB = (const float*)d_in[43];

  // ---- workspace (~35.5 MB; >=36.0 MB proven available) -------------------
  char* ws = (char*)d_ws;
  size_t o = 0;
  auto alloc = [&](size_t bytes)->void*{ void* p = ws + o; o += (bytes + 255)/256*256; return p; };
  bf16* Hb   = (bf16*)alloc((size_t)MP*256*2);   // 10.26 MB
  bf16* H2b  = (bf16*)alloc((size_t)MP*64*2);    //  2.56 MB
  bf16* X0   = (bf16*)alloc((size_t)MP*128*2);   //  5.13 MB x as bf16 (padded)
  int* OFFS  = (int*)alloc((size_t)(NN+1)*4);
  int* PERM  = (int*)alloc((size_t)NE*4);
  char* AR   = (char*)alloc((size_t)3*MP*128*2); // 15.38 MB arena
  bf16* WPK  = (bf16*)alloc((size_t)393216*2);   //  0.79 MB packed weights
  size_t need = o;
  // arena views
  bf16* Qc = (bf16*)AR;
  bf16* Kc = (bf16*)(AR + (size_t)MP*128*2);
  bf16* Vc = (bf16*)(AR + (size_t)2*MP*128*2);
  int*  CURS = (int*)AR;                         // setup only
  // L2 overlay (D=64)
  bf16* q2  = (bf16*)AR;
  bf16* k2  = (bf16*)(AR + (size_t)MP*64*2);
  bf16* v2  = (bf16*)(AR + (size_t)2*MP*64*2);
  bf16* LOG = (bf16*)(AR + (size_t)3*MP*64*2);       // NE*8 bf16
  float* Mx = (float*)(AR + (size_t)3*MP*64*2 + (size_t)NE*8*2);
  float* Dn = (float*)((char*)Mx + (size_t)NN*8*4);

  float* out_x  = (float*)d_out;                 // [NN,10]
  float* out_h4 = out_x + (size_t)NN*10;         // [NN,128]
  float* out_at = out_h4 + (size_t)NN*128;       // [NE,8]

  if (ws_size < need){
    fill_k<<<((size_t)out_size+255)/256, 256, 0, stream>>>((float*)d_out, out_size, 160.0f);
    return;
  }

  // ---- pack all weights into MFMA fragment order --------------------------
  const int KD[4] = {128,256,64,256};
  const int DD[4] = {256,64,256,128};
  bf16* Wp[4][4];
  {
    size_t off = 0;
    for (int l = 0; l < 4; l++)
      for (int j = 0; j < 4; j++){
        Wp[l][j] = WPK + off;
        int kd = KD[l]*DD[l];
        pack_w<<<(kd+255)/256, 256, 0, stream>>>(W[l][j], Wp[l][j], KD[l], DD[l]);
        off += kd;
      }
  }

  // ---- x -> bf16 padded ----
  cvtx_k<<<(MP*128)/256, 256, 0, stream>>>(x, X0);

  // ---- CSR by dst ----
  hipMemsetAsync(CURS, 0, (size_t)NN*4, stream);
  count_k<<<NE/256, 256, 0, stream>>>(ei, CURS, NE);
  exscan_k<<<1, 1024, 0, stream>>>(CURS, OFFS, NN);
  hipMemcpyAsync(CURS, OFFS, (size_t)NN*4, hipMemcpyDeviceToDevice, stream);
  scatter_k<<<NE/256, 256, 0, stream>>>(ei, CURS, PERM, NE);

  const float s32  = 0.1767766952966369f;
  const float s8   = 0.3535533905932738f;
  const float s128 = 0.0883883476483184f;
  const dim3 gm64(1, MP/64), gm128(2, MP/64);

  // ---- L1: 128 -> 256, H=8 (two 4-head tiles of 128 cols) -----------------
  for (int col = 0; col <= 128; col += 128){
    int tg0 = col >> 4;
    gemm_mfma<bf16><<<gm128,256,0,stream>>>(X0, (const short8v*)Wp[0][0], Bw[0][0]+col, Qc, 128, 16, tg0, 128, 0, MP);
    gemm_mfma<bf16><<<gm128,256,0,stream>>>(X0, (const short8v*)Wp[0][1], Bw[0][1]+col, Kc, 128, 16, tg0, 128, 0, MP);
    gemm_mfma<bf16><<<gm128,256,0,stream>>>(X0, (const short8v*)Wp[0][2], Bw[0][2]+col, Vc, 128, 16, tg0, 128, 0, MP);
    gemm_mfma<bf16><<<gm128,256,0,stream>>>(X0, (const short8v*)Wp[0][3], Bw[0][3]+col, Hb, 128, 16, tg0, 256, col, MP);
    fused_attn<128,4,bf16><<<NN/4,256,0,stream>>>(Qc,Kc,Vc, ei,PERM,OFFS, Hb,256,col,
                                                  nullptr,nullptr,nullptr, s32);
  }
  gelu_ln<4><<<NN/4,256,0,stream>>>(Hb, lng[0], lnb[0]);

  // ---- L2: 256 -> 64, H=8 (emits attn) ------------------------------------
  gemm_mfma<bf16><<<gm64,256,0,stream>>>(Hb, (const short8v*)Wp[1][0], Bw[1][0], q2, 256, 4, 0, 64, 0, MP);
  gemm_mfma<bf16><<<gm64,256,0,stream>>>(Hb, (const short8v*)Wp[1][1], Bw[1][1], k2, 256, 4, 0, 64, 0, MP);
  gemm_mfma<bf16><<<gm64,256,0,stream>>>(Hb, (const short8v*)Wp[1][2], Bw[1][2], v2, 256, 4, 0, 64, 0, MP);
  gemm_mfma<bf16><<<gm64,256,0,stream>>>(Hb, (const short8v*)Wp[1][3], Bw[1][3], H2b, 256, 4, 0, 64, 0, MP);
  fused_attn<64,8,bf16><<<NN/4,256,0,stream>>>(q2,k2,v2, ei,PERM,OFFS, H2b,64,0,
                                               LOG,Mx,Dn, s8);
  alpha8_k<<<NE*8/256,256,0,stream>>>(LOG, Mx, Dn, ei, PERM, out_at);
  gelu_ln<1><<<NN/4,256,0,stream>>>(H2b, lng[1], lnb[1]);

  // fc on h2 (independent of L3/L4)
  fc_k<<<NN/4,256,0,stream>>>(H2b, fcW, fcB, out_x, 64, 10);

  // ---- L3: 64 -> 256, H=8 (two 4-head tiles) -------------------------------
  for (int col = 0; col <= 128; col += 128){
    int tg0 = col >> 4;
    gemm_mfma<bf16><<<gm128,256,0,stream>>>(H2b, (const short8v*)Wp[2][0], Bw[2][0]+col, Qc, 64, 16, tg0, 128, 0, MP);
    gemm_mfma<bf16><<<gm128,256,0,stream>>>(H2b, (const short8v*)Wp[2][1], Bw[2][1]+col, Kc, 64, 16, tg0, 128, 0, MP);
    gemm_mfma<bf16><<<gm128,256,0,stream>>>(H2b, (const short8v*)Wp[2][2], Bw[2][2]+col, Vc, 64, 16, tg0, 128, 0, MP);
    gemm_mfma<bf16><<<gm128,256,0,stream>>>(H2b, (const short8v*)Wp[2][3], Bw[2][3]+col, Hb, 64, 16, tg0, 256, col, MP);
    fused_attn<128,4,bf16><<<NN/4,256,0,stream>>>(Qc,Kc,Vc, ei,PERM,OFFS, Hb,256,col,
                                                  nullptr,nullptr,nullptr, s32);
  }
  gelu_ln<4><<<NN/4,256,0,stream>>>(Hb, lng[2], lnb[2]);

  // ---- L4: 256 -> 128, H=1; skip+agg accumulate f32 in out_h4 -------------
  gemm_mfma<bf16><<<gm128,256,0,stream>>>(Hb, (const short8v*)Wp[3][0], Bw[3][0], Qc, 256, 8, 0, 128, 0, MP);
  gemm_mfma<bf16><<<gm128,256,0,stream>>>(Hb, (const short8v*)Wp[3][1], Bw[3][1], Kc, 256, 8, 0, 128, 0, MP);
  gemm_mfma<bf16><<<gm128,256,0,stream>>>(Hb, (const short8v*)Wp[3][2], Bw[3][2], Vc, 256, 8, 0, 128, 0, MP);
  gemm_mfma<float><<<gm128,256,0,stream>>>(Hb, (const short8v*)Wp[3][3], Bw[3][3], out_h4, 256, 8, 0, 128, 0, NN);
  fused_attn<128,1,float><<<NN/4,256,0,stream>>>(Qc,Kc,Vc, ei,PERM,OFFS, out_h4,128,0,
                                                 nullptr,nullptr,nullptr, s128);
  gelu_ln<2><<<NN/4,256,0,stream>>>(out_h4, lng[3], lnb[3]);
}

// Round 9
// 547.019 us; speedup vs baseline: 9.4955x; 1.3950x over previous
//
#include <hip/hip_runtime.h>
#include <hip/hip_bf16.h>
#include <math.h>

#define NN 20000
#define MP 20032            // NN padded to 64 (MFMA row tiles)
#define NE 320000

typedef __hip_bfloat16 bf16;
typedef __attribute__((ext_vector_type(8))) short short8v;   // 8 bf16 (4 VGPR)
typedef __attribute__((ext_vector_type(4))) float f32x4;

__device__ __forceinline__ float b2f(bf16 v){ return __bfloat162float(v); }
__device__ __forceinline__ bf16 f2b(float v){ return __float2bfloat16(v); }
__device__ __forceinline__ int clampi(int v, int lo, int hi){ return v < lo ? lo : (v > hi ? hi : v); }
__device__ __forceinline__ void stv(bf16* p, float v){ *p = f2b(v); }
__device__ __forceinline__ void stv(float* p, float v){ *p = v; }
__device__ __forceinline__ float ldv(const bf16* p){ return b2f(*p); }
__device__ __forceinline__ float ldv(const float* p){ return *p; }

// A-fragment loaders (16 consecutive-k bf16 elems, 8 per lane-group step)
__device__ __forceinline__ short8v ldA8(const bf16* p){
  return *reinterpret_cast<const short8v*>(p);
}
__device__ __forceinline__ short8v ldA8(const float* p){
  float4 a0 = *reinterpret_cast<const float4*>(p);
  float4 a1 = *reinterpret_cast<const float4*>(p + 4);
  short8v r;
  bf16 b;
  b = f2b(a0.x); r[0] = *(const short*)&b;
  b = f2b(a0.y); r[1] = *(const short*)&b;
  b = f2b(a0.z); r[2] = *(const short*)&b;
  b = f2b(a0.w); r[3] = *(const short*)&b;
  b = f2b(a1.x); r[4] = *(const short*)&b;
  b = f2b(a1.y); r[5] = *(const short*)&b;
  b = f2b(a1.z); r[6] = *(const short*)&b;
  b = f2b(a1.w); r[7] = *(const short*)&b;
  return r;
}

// ---- diagnostic fill ------------------------------------------------------
__global__ void fill_k(float* __restrict__ out, int n, float val){
  int i = blockIdx.x*blockDim.x + threadIdx.x;
  if (i < n) out[i] = val;
}

// ---- weight pack: W [K x D] f32 -> MFMA B-fragment order bf16 --------------
__global__ void pack_w(const float* __restrict__ W, bf16* __restrict__ Wp, int K, int D){
  int i = blockIdx.x*256 + threadIdx.x;
  if (i >= K*D) return;
  int j = i & 7, l = (i >> 3) & 63;
  int TG = D >> 4;
  int tg = (i >> 9) % TG, s = (i >> 9) / TG;
  int k = s*32 + (l >> 4)*8 + j, n = tg*16 + (l & 15);
  Wp[i] = f2b(W[(size_t)k*D + n]);
}

// ---- MFMA GEMM: Out[m, ocol+c] = sum_k X[m,k]*W[k,c] + bias[c] -------------
// 256 thr = 4 waves; 64x64 tile/block; A dtype templated (bf16 or f32).
template<typename AT, typename TO>
__global__ void gemm_mfma(const AT* __restrict__ X, const short8v* __restrict__ Wp,
                          const float* __restrict__ Bb, TO* __restrict__ Out,
                          int K, int TG, int tg0, int ldO, int ocol, int Mstore){
  int w = threadIdx.x >> 6, lane = threadIdx.x & 63;
  int n0 = blockIdx.x*64;
  size_t m0 = (size_t)blockIdx.y*64 + w*16;
  int lr = lane & 15, lk = lane >> 4;
  int ar = clampi((int)(m0 + lr), 0, NN-1);        // clamp A row (pad-safe)
  const AT* xp = X + (size_t)ar*K + lk*8;
  const short8v* wp = Wp + ((size_t)(tg0 + (n0 >> 4)))*64 + lane;
  f32x4 acc[4] = {f32x4{0,0,0,0},f32x4{0,0,0,0},f32x4{0,0,0,0},f32x4{0,0,0,0}};
  int steps = K >> 5;
  for (int s = 0; s < steps; s++){
    short8v a = ldA8(xp + s*32);
    const short8v* wrow = wp + (size_t)s*TG*64;
#pragma unroll
    for (int t = 0; t < 4; t++){
      short8v b = wrow[t*64];
      acc[t] = __builtin_amdgcn_mfma_f32_16x16x32_bf16(a, b, acc[t], 0, 0, 0);
    }
  }
#pragma unroll
  for (int t = 0; t < 4; t++){
    int col = n0 + t*16 + lr;
    float bias = Bb[col];
#pragma unroll
    for (int r = 0; r < 4; r++){
      int row = (int)m0 + lk*4 + r;
      if (row < Mstore) stv(&Out[(size_t)row*ldO + ocol + col], acc[t][r] + bias);
    }
  }
}

// ---- CSR build -------------------------------------------------------------
__global__ void count_k(const int* __restrict__ ei, int* __restrict__ cnt, int E){
  int e = blockIdx.x*blockDim.x + threadIdx.x;
  if (e < E){
    int d = clampi(ei[E + e], 0, NN-1);
    atomicAdd(&cnt[d], 1);
  }
}

__global__ void exscan_k(const int* __restrict__ cnt, int* __restrict__ off, int n){
  __shared__ int wtot[16];
  __shared__ int carrysh;
  int tid = threadIdx.x, lane = tid & 63, w = tid >> 6;
  if (tid == 0) carrysh = 0;
  __syncthreads();
  for (int base = 0; base < n; base += 1024){
    int i = base + tid;
    int v = (i < n) ? cnt[i] : 0;
    int s = v;
#pragma unroll
    for (int d = 1; d < 64; d <<= 1){
      int t = __shfl_up(s, d);
      if (lane >= d) s += t;
    }
    if (lane == 63) wtot[w] = s;
    __syncthreads();
    int woff = 0;
    for (int j = 0; j < w; j++) woff += wtot[j];
    int c = carrysh;
    if (i < n) off[i] = c + woff + s - v;
    __syncthreads();
    if (tid == 1023) carrysh = c + woff + s;
    __syncthreads();
  }
  if (threadIdx.x == 0) off[n] = carrysh;
}

__global__ void scatter_k(const int* __restrict__ ei, int* __restrict__ cur,
                          int* __restrict__ perm, int* __restrict__ srcs, int E){
  int e = blockIdx.x*blockDim.x + threadIdx.x;
  if (e >= E) return;
  int s = clampi(ei[e], 0, NN-1);
  int d = clampi(ei[E + e], 0, NN-1);
  int p = atomicAdd(&cur[d], 1);
  if (p >= 0 && p < E){ perm[p] = e; srcs[p] = s; }
}

// ---- fused per-node attention: dual-edge half-waves + K/V prefetch ---------
// One wave per dst node; lanes 0-31 = edge slot 0, lanes 32-63 = slot 1.
template<int D, int H, typename TO>
__global__ void fused_attn(const bf16* __restrict__ Q, const bf16* __restrict__ Kf,
                           const bf16* __restrict__ V, const int* __restrict__ srcs,
                           const int* __restrict__ offs,
                           TO* __restrict__ Xout, int ldO, int col0,
                           bf16* __restrict__ LOG, float* __restrict__ MxO,
                           float* __restrict__ DnO, float scale){
  constexpr int CPL = D/32;       // channels per (half-)lane
  constexpr int LPH = 32/H;       // lanes per head within a half-wave
  int node = blockIdx.x*4 + (threadIdx.x >> 6);
  if (node >= NN) return;
  int lane = threadIdx.x & 63;
  int hl = lane & 31;
  int slot = lane >> 5;
  float q[CPL];
  const bf16* qr = Q + (size_t)node*D + hl*CPL;
#pragma unroll
  for (int j = 0; j < CPL; j++) q[j] = b2f(qr[j]) * scale;
  float m = -INFINITY, den = 0.f;
  float acc[CPL];
#pragma unroll
  for (int j = 0; j < CPL; j++) acc[j] = 0.f;
  int s0 = offs[node], e0 = offs[node+1];
  int iters = (e0 - s0 + 1) >> 1;
  int i = s0 + slot;
  bool vcur = i < e0;
  int sc = vcur ? srcs[i] : 0;
  float kc[CPL], vc[CPL];
  {
    const bf16* kr = Kf + (size_t)sc*D + hl*CPL;
    const bf16* vr = V  + (size_t)sc*D + hl*CPL;
#pragma unroll
    for (int j = 0; j < CPL; j++){ kc[j] = b2f(kr[j]); vc[j] = b2f(vr[j]); }
  }
  for (int it = 0; it < iters; ++it){
    int inext = i + 2;
    bool vnxt = inext < e0;
    int sn = vnxt ? srcs[inext] : 0;
    float kn[CPL], vn[CPL];
    {
      const bf16* kr = Kf + (size_t)sn*D + hl*CPL;
      const bf16* vr = V  + (size_t)sn*D + hl*CPL;
#pragma unroll
      for (int j = 0; j < CPL; j++){ kn[j] = b2f(kr[j]); vn[j] = b2f(vr[j]); }
    }
    float t = 0.f;
#pragma unroll
    for (int j = 0; j < CPL; j++) t += q[j]*kc[j];
#pragma unroll
    for (int o = 1; o < LPH; o <<= 1) t += __shfl_xor(t, o);
    if (!vcur) t = -INFINITY;
    if (LOG && vcur && ((hl & (LPH-1)) == 0)) LOG[(size_t)i*H + hl/LPH] = f2b(t);
    float to = __shfl_xor(t, 32);
    float nm = fmaxf(m, fmaxf(t, to));
    float fe = __expf(m - nm);
    float pe = __expf(t - nm);
    den = den*fe + pe;
#pragma unroll
    for (int j = 0; j < CPL; j++) acc[j] = acc[j]*fe + pe*vc[j];
    m = nm;
    vcur = vnxt; i = inext;
#pragma unroll
    for (int j = 0; j < CPL; j++){ kc[j] = kn[j]; vc[j] = vn[j]; }
  }
  den += __shfl_xor(den, 32);
#pragma unroll
  for (int j = 0; j < CPL; j++) acc[j] += __shfl_xor(acc[j], 32);
  float inv = 1.f/(den + 1e-16f);
  if (slot == 0){
    TO* o = Xout + (size_t)node*ldO + col0 + hl*CPL;
#pragma unroll
    for (int j = 0; j < CPL; j++) stv(&o[j], ldv(&o[j]) + acc[j]*inv);
    if (MxO && ((hl & (LPH-1)) == 0)){
      MxO[node*H + hl/LPH] = m;
      DnO[node*H + hl/LPH] = den;
    }
  }
}

// ---- alpha scatter for L2 --------------------------------------------------
__global__ void alpha8_k(const bf16* __restrict__ LOG, const float* __restrict__ Mx,
                         const float* __restrict__ Dn, const int* __restrict__ ei,
                         const int* __restrict__ perm, float* __restrict__ attn){
  size_t t = (size_t)blockIdx.x*blockDim.x + threadIdx.x;
  if (t >= (size_t)NE*8) return;
  int pos = (int)(t >> 3), h = (int)(t & 7);
  int e = perm[pos];
  int node = ei[NE + e];
  float a = __expf(b2f(LOG[t]) - Mx[node*8 + h]) / (Dn[node*8 + h] + 1e-16f);
  attn[(size_t)e*8 + h] = a;
}

// ---- fused exact-GELU + LayerNorm, in place --------------------------------
template<int CPL, typename T>
__global__ void gelu_ln(T* __restrict__ X, const float* __restrict__ G,
                        const float* __restrict__ Bt){
  int node = blockIdx.x*4 + (threadIdx.x >> 6);
  if (node >= NN) return;
  constexpr int D = CPL*64;
  int lane = threadIdx.x & 63;
  T* xr = X + (size_t)node*D + lane*CPL;
  float v[CPL]; float s = 0.f;
#pragma unroll
  for (int j = 0; j < CPL; j++){
    float t = ldv(&xr[j]);
    float ge = 0.5f*t*(1.f + erff(t*0.70710678118654752f));
    v[j] = ge; s += ge;
  }
#pragma unroll
  for (int off = 1; off < 64; off <<= 1) s += __shfl_xor(s, off);
  float mu = s * (1.f/D);
  float q = 0.f;
#pragma unroll
  for (int j = 0; j < CPL; j++){ float d = v[j]-mu; q += d*d; }
#pragma unroll
  for (int off = 1; off < 64; off <<= 1) q += __shfl_xor(q, off);
  float inv = 1.f / sqrtf(q*(1.f/D) + 1e-5f);
#pragma unroll
  for (int j = 0; j < CPL; j++){
    int c = lane*CPL + j;
    stv(&xr[j], G[c]*(v[j]-mu)*inv + Bt[c]);
  }
}

// ---- tiny fc ----------------------------------------------------------------
__global__ void fc_k(const bf16* __restrict__ X, const float* __restrict__ W,
                     const float* __restrict__ B, float* __restrict__ Out,
                     int K, int D){
  int m = blockIdx.x*4 + (threadIdx.x >> 6);
  int lane = threadIdx.x & 63;
  if (m >= NN || lane >= D) return;
  float acc = B[lane];
  for (int k = 0; k < K; k++) acc += b2f(X[(size_t)m*K + k]) * W[(size_t)k*D + lane];
  Out[(size_t)m*D + lane] = acc;
}

extern "C" void kernel_launch(void* const* d_in, const int* in_sizes, int n_in,
                              void* d_out, int out_size, void* d_ws, size_t ws_size,
                              hipStream_t stream){
  int code = 0;
  if (n_in != 44) code = 100;
  else {
    const int wsz[4] = {32768,16384,16384,32768};
    const int bsz[4] = {256,64,256,128};
    bool ok = in_sizes[0] == NN*128 && in_sizes[1] == 2*NE
           && in_sizes[42] == 640 && in_sizes[43] == 10;
    for (int l = 0; l < 4 && ok; l++){
      for (int j = 0; j < 4; j++)
        ok = ok && in_sizes[2+l*8+j] == wsz[l] && in_sizes[2+l*8+4+j] == bsz[l];
      ok = ok && in_sizes[34+2*l] == bsz[l] && in_sizes[35+2*l] == bsz[l];
    }
    if (!ok) code = 140;
  }
  if (code){
    fill_k<<<((size_t)out_size+255)/256, 256, 0, stream>>>((float*)d_out, out_size, (float)code);
    return;
  }

  const float* x = (const float*)d_in[0];
  const int*   ei = (const int*)d_in[1];
  const float *W[4][4], *Bw[4][4], *lng[4], *lnb[4];
  for (int l = 0; l < 4; l++){
    for (int j = 0; j < 4; j++){
      W[l][j]  = (const float*)d_in[2 + l*8 + j];      // Wq,Wk,Wv,Ws
      Bw[l][j] = (const float*)d_in[2 + l*8 + 4 + j];  // bq,bk,bv,bs
    }
    lng[l] = (const float*)d_in[34 + 2*l];
    lnb[l] = (const float*)d_in[35 + 2*l];
  }
  const float* fcW = (const float*)d_in[42];
  const float* fcB = (const float*)d_in[43];

  // ---- workspace (~31.6 MB; >=36.1 MB proven available) -------------------
  char* ws = (char*)d_ws;
  size_t o = 0;
  auto alloc = [&](size_t bytes)->void*{ void* p = ws + o; o += (bytes + 255)/256*256; return p; };
  bf16* Hb   = (bf16*)alloc((size_t)MP*256*2);   // 10.26 MB
  bf16* H2b  = (bf16*)alloc((size_t)MP*64*2);    //  2.56 MB
  int* OFFS  = (int*)alloc((size_t)(NN+1)*4);
  int* PERM  = (int*)alloc((size_t)NE*4);
  int* SRCS  = (int*)alloc((size_t)NE*4);
  char* AR   = (char*)alloc((size_t)3*MP*128*2); // 15.38 MB arena
  bf16* WPK  = (bf16*)alloc((size_t)393216*2);   //  0.79 MB packed weights
  size_t need = o;
  // arena views
  bf16* Qc = (bf16*)AR;
  bf16* Kc = (bf16*)(AR + (size_t)MP*128*2);
  bf16* Vc = (bf16*)(AR + (size_t)2*MP*128*2);
  int*  CURS = (int*)AR;                         // setup only
  // L2 overlay (D=64)
  bf16* q2  = (bf16*)AR;
  bf16* k2  = (bf16*)(AR + (size_t)MP*64*2);
  bf16* v2  = (bf16*)(AR + (size_t)2*MP*64*2);
  bf16* LOG = (bf16*)(AR + (size_t)3*MP*64*2);       // NE*8 bf16
  float* Mx = (float*)(AR + (size_t)3*MP*64*2 + (size_t)NE*8*2);
  float* Dn = (float*)((char*)Mx + (size_t)NN*8*4);

  float* out_x  = (float*)d_out;                 // [NN,10]
  float* out_h4 = out_x + (size_t)NN*10;         // [NN,128]
  float* out_at = out_h4 + (size_t)NN*128;       // [NE,8]

  if (ws_size < need){
    fill_k<<<((size_t)out_size+255)/256, 256, 0, stream>>>((float*)d_out, out_size, 160.0f);
    return;
  }

  // ---- pack all weights into MFMA fragment order --------------------------
  const int KD[4] = {128,256,64,256};
  const int DD[4] = {256,64,256,128};
  bf16* Wp[4][4];
  {
    size_t off = 0;
    for (int l = 0; l < 4; l++)
      for (int j = 0; j < 4; j++){
        Wp[l][j] = WPK + off;
        int kd = KD[l]*DD[l];
        pack_w<<<(kd+255)/256, 256, 0, stream>>>(W[l][j], Wp[l][j], KD[l], DD[l]);
        off += kd;
      }
  }

  // ---- CSR by dst ----
  hipMemsetAsync(CURS, 0, (size_t)NN*4, stream);
  count_k<<<NE/256, 256, 0, stream>>>(ei, CURS, NE);
  exscan_k<<<1, 1024, 0, stream>>>(CURS, OFFS, NN);
  hipMemcpyAsync(CURS, OFFS, (size_t)NN*4, hipMemcpyDeviceToDevice, stream);
  scatter_k<<<NE/256, 256, 0, stream>>>(ei, CURS, PERM, SRCS, NE);

  const float s32  = 0.1767766952966369f;
  const float s8   = 0.3535533905932738f;
  const float s128 = 0.0883883476483184f;
  const dim3 gm64(1, MP/64), gm128(2, MP/64);

  // ---- L1: 128 -> 256, H=8 (two 4-head tiles of 128 cols), A = x (f32) ----
  for (int col = 0; col <= 128; col += 128){
    int tg0 = col >> 4;
    gemm_mfma<float,bf16><<<gm128,256,0,stream>>>(x, (const short8v*)Wp[0][0], Bw[0][0]+col, Qc, 128, 16, tg0, 128, 0, MP);
    gemm_mfma<float,bf16><<<gm128,256,0,stream>>>(x, (const short8v*)Wp[0][1], Bw[0][1]+col, Kc, 128, 16, tg0, 128, 0, MP);
    gemm_mfma<float,bf16><<<gm128,256,0,stream>>>(x, (const short8v*)Wp[0][2], Bw[0][2]+col, Vc, 128, 16, tg0, 128, 0, MP);
    gemm_mfma<float,bf16><<<gm128,256,0,stream>>>(x, (const short8v*)Wp[0][3], Bw[0][3]+col, Hb, 128, 16, tg0, 256, col, MP);
    fused_attn<128,4,bf16><<<NN/4,256,0,stream>>>(Qc,Kc,Vc, SRCS,OFFS, Hb,256,col,
                                                  nullptr,nullptr,nullptr, s32);
  }
  gelu_ln<4><<<NN/4,256,0,stream>>>(Hb, lng[0], lnb[0]);

  // ---- L2: 256 -> 64, H=8 (emits attn) ------------------------------------
  gemm_mfma<bf16,bf16><<<gm64,256,0,stream>>>(Hb, (const short8v*)Wp[1][0], Bw[1][0], q2, 256, 4, 0, 64, 0, MP);
  gemm_mfma<bf16,bf16><<<gm64,256,0,stream>>>(Hb, (const short8v*)Wp[1][1], Bw[1][1], k2, 256, 4, 0, 64, 0, MP);
  gemm_mfma<bf16,bf16><<<gm64,256,0,stream>>>(Hb, (const short8v*)Wp[1][2], Bw[1][2], v2, 256, 4, 0, 64, 0, MP);
  gemm_mfma<bf16,bf16><<<gm64,256,0,stream>>>(Hb, (const short8v*)Wp[1][3], Bw[1][3], H2b, 256, 4, 0, 64, 0, MP);
  fused_attn<64,8,bf16><<<NN/4,256,0,stream>>>(q2,k2,v2, SRCS,OFFS, H2b,64,0,
                                               LOG,Mx,Dn, s8);
  alpha8_k<<<NE*8/256,256,0,stream>>>(LOG, Mx, Dn, ei, PERM, out_at);
  gelu_ln<1><<<NN/4,256,0,stream>>>(H2b, lng[1], lnb[1]);

  // fc on h2 (independent of L3/L4)
  fc_k<<<NN/4,256,0,stream>>>(H2b, fcW, fcB, out_x, 64, 10);

  // ---- L3: 64 -> 256, H=8 (two 4-head tiles) -------------------------------
  for (int col = 0; col <= 128; col += 128){
    int tg0 = col >> 4;
    gemm_mfma<bf16,bf16><<<gm128,256,0,stream>>>(H2b, (const short8v*)Wp[2][0], Bw[2][0]+col, Qc, 64, 16, tg0, 128, 0, MP);
    gemm_mfma<bf16,bf16><<<gm128,256,0,stream>>>(H2b, (const short8v*)Wp[2][1], Bw[2][1]+col, Kc, 64, 16, tg0, 128, 0, MP);
    gemm_mfma<bf16,bf16><<<gm128,256,0,stream>>>(H2b, (const short8v*)Wp[2][2], Bw[2][2]+col, Vc, 64, 16, tg0, 128, 0, MP);
    gemm_mfma<bf16,bf16><<<gm128,256,0,stream>>>(H2b, (const short8v*)Wp[2][3], Bw[2][3]+col, Hb, 64, 16, tg0, 256, col, MP);
    fused_attn<128,4,bf16><<<NN/4,256,0,stream>>>(Qc,Kc,Vc, SRCS,OFFS, Hb,256,col,
                                                  nullptr,nullptr,nullptr, s32);
  }
  gelu_ln<4><<<NN/4,256,0,stream>>>(Hb, lng[2], lnb[2]);

  // ---- L4: 256 -> 128, H=1; skip+agg accumulate f32 in out_h4 -------------
  gemm_mfma<bf16,bf16><<<gm128,256,0,stream>>>(Hb, (const short8v*)Wp[3][0], Bw[3][0], Qc, 256, 8, 0, 128, 0, MP);
  gemm_mfma<bf16,bf16><<<gm128,256,0,stream>>>(Hb, (const short8v*)Wp[3][1], Bw[3][1], Kc, 256, 8, 0, 128, 0, MP);
  gemm_mfma<bf16,bf16><<<gm128,256,0,stream>>>(Hb, (const short8v*)Wp[3][2], Bw[3][2], Vc, 256, 8, 0, 128, 0, MP);
  gemm_mfma<bf16,float><<<gm128,256,0,stream>>>(Hb, (const short8v*)Wp[3][3], Bw[3][3], out_h4, 256, 8, 0, 128, 0, NN);
  fused_attn<128,1,float><<<NN/4,256,0,stream>>>(Qc,Kc,Vc, SRCS,OFFS, out_h4,128,0,
                                                 nullptr,nullptr,nullptr, s128);
  gelu_ln<2><<<NN/4,256,0,stream>>>(out_h4, lng[3], lnb[3]);
}

// Round 10
// 398.172 us; speedup vs baseline: 13.0451x; 1.3738x over previous
//
#include <hip/hip_runtime.h>
#include <hip/hip_bf16.h>
#include <math.h>

#define NN 20000
#define MP 20032            // NN padded to 64 (MFMA row tiles)
#define NE 320000

typedef __hip_bfloat16 bf16;
typedef __attribute__((ext_vector_type(8))) short short8v;   // 8 bf16 (4 VGPR)
typedef __attribute__((ext_vector_type(4))) short short4v;
typedef __attribute__((ext_vector_type(4))) float f32x4;

__device__ __forceinline__ float b2f(bf16 v){ return __bfloat162float(v); }
__device__ __forceinline__ bf16 f2b(float v){ return __float2bfloat16(v); }
__device__ __forceinline__ float bfbits(short s){
  return __uint_as_float(((unsigned)(unsigned short)s) << 16);
}
__device__ __forceinline__ int clampi(int v, int lo, int hi){ return v < lo ? lo : (v > hi ? hi : v); }
__device__ __forceinline__ void stv(bf16* p, float v){ *p = f2b(v); }
__device__ __forceinline__ void stv(float* p, float v){ *p = v; }
__device__ __forceinline__ float ldv(const bf16* p){ return b2f(*p); }
__device__ __forceinline__ float ldv(const float* p){ return *p; }

// vector row loader: CPL consecutive bf16 -> f32
template<int CPL>
__device__ __forceinline__ void ldrow(const bf16* p, float* o){
  if constexpr (CPL == 8){
    short8v v = *reinterpret_cast<const short8v*>(p);
#pragma unroll
    for (int j = 0; j < 8; j++) o[j] = bfbits(v[j]);
  } else {
    short4v v = *reinterpret_cast<const short4v*>(p);
#pragma unroll
    for (int j = 0; j < 4; j++) o[j] = bfbits(v[j]);
  }
}

// A-fragment loaders (8 consecutive-k elems per lane)
__device__ __forceinline__ short8v ldA8(const bf16* p){
  return *reinterpret_cast<const short8v*>(p);
}
__device__ __forceinline__ short8v ldA8(const float* p){
  float4 a0 = *reinterpret_cast<const float4*>(p);
  float4 a1 = *reinterpret_cast<const float4*>(p + 4);
  short8v r;
  bf16 b;
  b = f2b(a0.x); r[0] = *(const short*)&b;
  b = f2b(a0.y); r[1] = *(const short*)&b;
  b = f2b(a0.z); r[2] = *(const short*)&b;
  b = f2b(a0.w); r[3] = *(const short*)&b;
  b = f2b(a1.x); r[4] = *(const short*)&b;
  b = f2b(a1.y); r[5] = *(const short*)&b;
  b = f2b(a1.z); r[6] = *(const short*)&b;
  b = f2b(a1.w); r[7] = *(const short*)&b;
  return r;
}

// ---- diagnostic fill ------------------------------------------------------
__global__ void fill_k(float* __restrict__ out, int n, float val){
  int i = blockIdx.x*blockDim.x + threadIdx.x;
  if (i < n) out[i] = val;
}

// ---- weight pack: W [K x D] f32 -> MFMA B-fragment order bf16 --------------
__global__ void pack_w(const float* __restrict__ W, bf16* __restrict__ Wp, int K, int D){
  int i = blockIdx.x*256 + threadIdx.x;
  if (i >= K*D) return;
  int j = i & 7, l = (i >> 3) & 63;
  int TG = D >> 4;
  int tg = (i >> 9) % TG, s = (i >> 9) / TG;
  int k = s*32 + (l >> 4)*8 + j, n = tg*16 + (l & 15);
  Wp[i] = f2b(W[(size_t)k*D + n]);
}

// ---- fused QKVS MFMA GEMM: 4 outputs sharing the A matrix ------------------
// 256 thr = 4 waves; 64x64 tile/block; 16 MFMA per K-step.
template<typename AT, typename TS>
__global__ void gemm_qkvs(const AT* __restrict__ X,
    const short8v* __restrict__ WQ, const short8v* __restrict__ WK,
    const short8v* __restrict__ WV, const short8v* __restrict__ WS,
    const float* __restrict__ bQ, const float* __restrict__ bK,
    const float* __restrict__ bV, const float* __restrict__ bS,
    bf16* __restrict__ Qo, bf16* __restrict__ Ko, bf16* __restrict__ Vo,
    TS* __restrict__ So,
    int K, int TG, int tg0, int ldQKV, int ldS, int ocolS, int MstoreS){
  int w = threadIdx.x >> 6, lane = threadIdx.x & 63;
  int n0 = blockIdx.x*64;
  size_t m0 = (size_t)blockIdx.y*64 + w*16;
  int lr = lane & 15, lk = lane >> 4;
  int ar = clampi((int)(m0 + lr), 0, NN-1);
  const AT* xp = X + (size_t)ar*K + lk*8;
  size_t wo = ((size_t)(tg0 + (n0 >> 4)))*64 + lane;
  f32x4 acc[4][4];
#pragma unroll
  for (int j = 0; j < 4; j++)
#pragma unroll
    for (int t = 0; t < 4; t++) acc[j][t] = f32x4{0,0,0,0};
  int steps = K >> 5;
  for (int s = 0; s < steps; s++){
    short8v a = ldA8(xp + s*32);
    size_t ro = wo + (size_t)s*TG*64;
#pragma unroll
    for (int t = 0; t < 4; t++){
      size_t idx = ro + t*64;
      acc[0][t] = __builtin_amdgcn_mfma_f32_16x16x32_bf16(a, WQ[idx], acc[0][t], 0, 0, 0);
      acc[1][t] = __builtin_amdgcn_mfma_f32_16x16x32_bf16(a, WK[idx], acc[1][t], 0, 0, 0);
      acc[2][t] = __builtin_amdgcn_mfma_f32_16x16x32_bf16(a, WV[idx], acc[2][t], 0, 0, 0);
      acc[3][t] = __builtin_amdgcn_mfma_f32_16x16x32_bf16(a, WS[idx], acc[3][t], 0, 0, 0);
    }
  }
#pragma unroll
  for (int t = 0; t < 4; t++){
    int col = n0 + t*16 + lr;
    float b0 = bQ[col], b1 = bK[col], b2 = bV[col], b3 = bS[col];
#pragma unroll
    for (int r = 0; r < 4; r++){
      size_t row = m0 + lk*4 + r;
      Qo[row*ldQKV + col] = f2b(acc[0][t][r] + b0);
      Ko[row*ldQKV + col] = f2b(acc[1][t][r] + b1);
      Vo[row*ldQKV + col] = f2b(acc[2][t][r] + b2);
      if ((int)row < MstoreS) stv(&So[row*(size_t)ldS + ocolS + col], acc[3][t][r] + b3);
    }
  }
}

// ---- CSR build -------------------------------------------------------------
__global__ void count_k(const int* __restrict__ ei, int* __restrict__ cnt, int E){
  int e = blockIdx.x*blockDim.x + threadIdx.x;
  if (e < E){
    int d = clampi(ei[E + e], 0, NN-1);
    atomicAdd(&cnt[d], 1);
  }
}

__global__ void exscan_k(const int* __restrict__ cnt, int* __restrict__ off, int n){
  __shared__ int wtot[16];
  __shared__ int carrysh;
  int tid = threadIdx.x, lane = tid & 63, w = tid >> 6;
  if (tid == 0) carrysh = 0;
  __syncthreads();
  for (int base = 0; base < n; base += 1024){
    int i = base + tid;
    int v = (i < n) ? cnt[i] : 0;
    int s = v;
#pragma unroll
    for (int d = 1; d < 64; d <<= 1){
      int t = __shfl_up(s, d);
      if (lane >= d) s += t;
    }
    if (lane == 63) wtot[w] = s;
    __syncthreads();
    int woff = 0;
    for (int j = 0; j < w; j++) woff += wtot[j];
    int c = carrysh;
    if (i < n) off[i] = c + woff + s - v;
    __syncthreads();
    if (tid == 1023) carrysh = c + woff + s;
    __syncthreads();
  }
  if (threadIdx.x == 0) off[n] = carrysh;
}

__global__ void scatter_k(const int* __restrict__ ei, int* __restrict__ cur,
                          int* __restrict__ perm, int* __restrict__ srcs, int E){
  int e = blockIdx.x*blockDim.x + threadIdx.x;
  if (e >= E) return;
  int s = clampi(ei[e], 0, NN-1);
  int d = clampi(ei[E + e], 0, NN-1);
  int p = atomicAdd(&cur[d], 1);
  if (p >= 0 && p < E){ perm[p] = e; srcs[p] = s; }
}

// ---- fused per-node attention: quad-edge quarter-waves + prefetch ----------
// One wave per dst node; 4 slots of 16 lanes each process 4 edges in flight.
template<int D, int H, typename TO>
__global__ void fused_attn(const bf16* __restrict__ Q, const bf16* __restrict__ Kf,
                           const bf16* __restrict__ V, const int* __restrict__ srcs,
                           const int* __restrict__ offs,
                           TO* __restrict__ Xout, int ldO, int col0,
                           bf16* __restrict__ LOG, float* __restrict__ MxO,
                           float* __restrict__ DnO, float scale){
  constexpr int CPL = D/16;       // channels per lane (quarter-wave of 16)
  constexpr int LPH = 16/H;       // lanes per head within a slot
  int node = blockIdx.x*4 + (threadIdx.x >> 6);
  if (node >= NN) return;
  int lane = threadIdx.x & 63;
  int hl = lane & 15;
  int slot = lane >> 4;
  float q[CPL];
  {
    float tmp[CPL];
    ldrow<CPL>(Q + (size_t)node*D + hl*CPL, tmp);
#pragma unroll
    for (int j = 0; j < CPL; j++) q[j] = tmp[j] * scale;
  }
  float m = -INFINITY, den = 0.f;
  float acc[CPL];
#pragma unroll
  for (int j = 0; j < CPL; j++) acc[j] = 0.f;
  int s0 = offs[node], e0 = offs[node+1];
  int i = s0 + slot;
  bool vcur = i < e0;
  int sc = vcur ? srcs[i] : 0;
  float kc[CPL], vc[CPL];
  ldrow<CPL>(Kf + (size_t)sc*D + hl*CPL, kc);
  ldrow<CPL>(V  + (size_t)sc*D + hl*CPL, vc);
  int iters = (e0 - s0 + 3) >> 2;
  for (int it = 0; it < iters; ++it){
    int inext = i + 4;
    bool vnxt = inext < e0;
    int sn = vnxt ? srcs[inext] : 0;
    float kn[CPL], vn[CPL];
    ldrow<CPL>(Kf + (size_t)sn*D + hl*CPL, kn);
    ldrow<CPL>(V  + (size_t)sn*D + hl*CPL, vn);
    float t = 0.f;
#pragma unroll
    for (int j = 0; j < CPL; j++) t += q[j]*kc[j];
#pragma unroll
    for (int o = 1; o < LPH; o <<= 1) t += __shfl_xor(t, o);
    if (!vcur) t = -INFINITY;
    if (LOG && vcur && ((hl & (LPH-1)) == 0)) LOG[(size_t)i*H + hl/LPH] = f2b(t);
    float tm = fmaxf(t, __shfl_xor(t, 16));
    tm = fmaxf(tm, __shfl_xor(tm, 32));
    float nm = fmaxf(m, tm);
    float fe = __expf(m - nm);
    float pe = __expf(t - nm);
    den = den*fe + pe;
#pragma unroll
    for (int j = 0; j < CPL; j++) acc[j] = acc[j]*fe + pe*vc[j];
    m = nm;
    vcur = vnxt; i = inext;
#pragma unroll
    for (int j = 0; j < CPL; j++){ kc[j] = kn[j]; vc[j] = vn[j]; }
  }
  den += __shfl_xor(den, 16);
  den += __shfl_xor(den, 32);
#pragma unroll
  for (int j = 0; j < CPL; j++){
    acc[j] += __shfl_xor(acc[j], 16);
    acc[j] += __shfl_xor(acc[j], 32);
  }
  float inv = 1.f/(den + 1e-16f);
  if (slot == 0){
    TO* o = Xout + (size_t)node*ldO + col0 + hl*CPL;
#pragma unroll
    for (int j = 0; j < CPL; j++) stv(&o[j], ldv(&o[j]) + acc[j]*inv);
    if (MxO && ((hl & (LPH-1)) == 0)){
      MxO[node*H + hl/LPH] = m;
      DnO[node*H + hl/LPH] = den;
    }
  }
}

// ---- alpha scatter for L2 --------------------------------------------------
__global__ void alpha8_k(const bf16* __restrict__ LOG, const float* __restrict__ Mx,
                         const float* __restrict__ Dn, const int* __restrict__ ei,
                         const int* __restrict__ perm, float* __restrict__ attn){
  size_t t = (size_t)blockIdx.x*blockDim.x + threadIdx.x;
  if (t >= (size_t)NE*8) return;
  int pos = (int)(t >> 3), h = (int)(t & 7);
  int e = perm[pos];
  int node = ei[NE + e];
  float a = __expf(b2f(LOG[t]) - Mx[node*8 + h]) / (Dn[node*8 + h] + 1e-16f);
  attn[(size_t)e*8 + h] = a;
}

// ---- fused exact-GELU + LayerNorm, in place --------------------------------
template<int CPL, typename T>
__global__ void gelu_ln(T* __restrict__ X, const float* __restrict__ G,
                        const float* __restrict__ Bt){
  int node = blockIdx.x*4 + (threadIdx.x >> 6);
  if (node >= NN) return;
  constexpr int D = CPL*64;
  int lane = threadIdx.x & 63;
  T* xr = X + (size_t)node*D + lane*CPL;
  float v[CPL]; float s = 0.f;
#pragma unroll
  for (int j = 0; j < CPL; j++){
    float t = ldv(&xr[j]);
    float ge = 0.5f*t*(1.f + erff(t*0.70710678118654752f));
    v[j] = ge; s += ge;
  }
#pragma unroll
  for (int off = 1; off < 64; off <<= 1) s += __shfl_xor(s, off);
  float mu = s * (1.f/D);
  float q = 0.f;
#pragma unroll
  for (int j = 0; j < CPL; j++){ float d = v[j]-mu; q += d*d; }
#pragma unroll
  for (int off = 1; off < 64; off <<= 1) q += __shfl_xor(q, off);
  float inv = 1.f / sqrtf(q*(1.f/D) + 1e-5f);
#pragma unroll
  for (int j = 0; j < CPL; j++){
    int c = lane*CPL + j;
    stv(&xr[j], G[c]*(v[j]-mu)*inv + Bt[c]);
  }
}

// ---- tiny fc ----------------------------------------------------------------
__global__ void fc_k(const bf16* __restrict__ X, const float* __restrict__ W,
                     const float* __restrict__ B, float* __restrict__ Out,
                     int K, int D){
  int m = blockIdx.x*4 + (threadIdx.x >> 6);
  int lane = threadIdx.x & 63;
  if (m >= NN || lane >= D) return;
  float acc = B[lane];
  for (int k = 0; k < K; k++) acc += b2f(X[(size_t)m*K + k]) * W[(size_t)k*D + lane];
  Out[(size_t)m*D + lane] = acc;
}

extern "C" void kernel_launch(void* const* d_in, const int* in_sizes, int n_in,
                              void* d_out, int out_size, void* d_ws, size_t ws_size,
                              hipStream_t stream){
  int code = 0;
  if (n_in != 44) code = 100;
  else {
    const int wsz[4] = {32768,16384,16384,32768};
    const int bsz[4] = {256,64,256,128};
    bool ok = in_sizes[0] == NN*128 && in_sizes[1] == 2*NE
           && in_sizes[42] == 640 && in_sizes[43] == 10;
    for (int l = 0; l < 4 && ok; l++){
      for (int j = 0; j < 4; j++)
        ok = ok && in_sizes[2+l*8+j] == wsz[l] && in_sizes[2+l*8+4+j] == bsz[l];
      ok = ok && in_sizes[34+2*l] == bsz[l] && in_sizes[35+2*l] == bsz[l];
    }
    if (!ok) code = 140;
  }
  if (code){
    fill_k<<<((size_t)out_size+255)/256, 256, 0, stream>>>((float*)d_out, out_size, (float)code);
    return;
  }

  const float* x = (const float*)d_in[0];
  const int*   ei = (const int*)d_in[1];
  const float *W[4][4], *Bw[4][4], *lng[4], *lnb[4];
  for (int l = 0; l < 4; l++){
    for (int j = 0; j < 4; j++){
      W[l][j]  = (const float*)d_in[2 + l*8 + j];      // Wq,Wk,Wv,Ws
      Bw[l][j] = (const float*)d_in[2 + l*8 + 4 + j];  // bq,bk,bv,bs
    }
    lng[l] = (const float*)d_in[34 + 2*l];
    lnb[l] = (const float*)d_in[35 + 2*l];
  }
  const float* fcW = (const float*)d_in[42];
  const float* fcB = (const float*)d_in[43];

  // ---- workspace (~31.6 MB) ------------------------------------------------
  char* ws = (char*)d_ws;
  size_t o = 0;
  auto alloc = [&](size_t bytes)->void*{ void* p = ws + o; o += (bytes + 255)/256*256; return p; };
  bf16* Hb   = (bf16*)alloc((size_t)MP*256*2);   // 10.26 MB
  bf16* H2b  = (bf16*)alloc((size_t)MP*64*2);    //  2.56 MB
  int* OFFS  = (int*)alloc((size_t)(NN+1)*4);
  int* PERM  = (int*)alloc((size_t)NE*4);
  int* SRCS  = (int*)alloc((size_t)NE*4);
  char* AR   = (char*)alloc((size_t)3*MP*128*2); // 15.38 MB arena
  bf16* WPK  = (bf16*)alloc((size_t)393216*2);   //  0.79 MB packed weights
  size_t need = o;
  // arena views
  bf16* Qc = (bf16*)AR;
  bf16* Kc = (bf16*)(AR + (size_t)MP*128*2);
  bf16* Vc = (bf16*)(AR + (size_t)2*MP*128*2);
  int*  CURS = (int*)AR;                         // setup only
  // L2 overlay (D=64)
  bf16* q2  = (bf16*)AR;
  bf16* k2  = (bf16*)(AR + (size_t)MP*64*2);
  bf16* v2  = (bf16*)(AR + (size_t)2*MP*64*2);
  bf16* LOG = (bf16*)(AR + (size_t)3*MP*64*2);       // NE*8 bf16
  float* Mx = (float*)(AR + (size_t)3*MP*64*2 + (size_t)NE*8*2);
  float* Dn = (float*)((char*)Mx + (size_t)NN*8*4);

  float* out_x  = (float*)d_out;                 // [NN,10]
  float* out_h4 = out_x + (size_t)NN*10;         // [NN,128]
  float* out_at = out_h4 + (size_t)NN*128;       // [NE,8]

  if (ws_size < need){
    fill_k<<<((size_t)out_size+255)/256, 256, 0, stream>>>((float*)d_out, out_size, 160.0f);
    return;
  }

  // ---- pack all weights into MFMA fragment order --------------------------
  const int KD[4] = {128,256,64,256};
  const int DD[4] = {256,64,256,128};
  bf16* Wp[4][4];
  {
    size_t off = 0;
    for (int l = 0; l < 4; l++)
      for (int j = 0; j < 4; j++){
        Wp[l][j] = WPK + off;
        int kd = KD[l]*DD[l];
        pack_w<<<(kd+255)/256, 256, 0, stream>>>(W[l][j], Wp[l][j], KD[l], DD[l]);
        off += kd;
      }
  }

  // ---- CSR by dst ----
  hipMemsetAsync(CURS, 0, (size_t)NN*4, stream);
  count_k<<<NE/256, 256, 0, stream>>>(ei, CURS, NE);
  exscan_k<<<1, 1024, 0, stream>>>(CURS, OFFS, NN);
  hipMemcpyAsync(CURS, OFFS, (size_t)NN*4, hipMemcpyDeviceToDevice, stream);
  scatter_k<<<NE/256, 256, 0, stream>>>(ei, CURS, PERM, SRCS, NE);

  const float s32  = 0.1767766952966369f;
  const float s8   = 0.3535533905932738f;
  const float s128 = 0.0883883476483184f;
  const dim3 gm64(1, MP/64), gm128(2, MP/64);

  // ---- L1: 128 -> 256, H=8 (two 4-head col tiles), A = x (f32) ------------
  for (int col = 0; col <= 128; col += 128){
    int tg0 = col >> 4;
    gemm_qkvs<float,bf16><<<gm128,256,0,stream>>>(x,
        (const short8v*)Wp[0][0], (const short8v*)Wp[0][1],
        (const short8v*)Wp[0][2], (const short8v*)Wp[0][3],
        Bw[0][0]+col, Bw[0][1]+col, Bw[0][2]+col, Bw[0][3]+col,
        Qc, Kc, Vc, Hb, 128, 16, tg0, 128, 256, col, MP);
    fused_attn<128,4,bf16><<<NN/4,256,0,stream>>>(Qc,Kc,Vc, SRCS,OFFS, Hb,256,col,
                                                  nullptr,nullptr,nullptr, s32);
  }
  gelu_ln<4><<<NN/4,256,0,stream>>>(Hb, lng[0], lnb[0]);

  // ---- L2: 256 -> 64, H=8 (emits attn) ------------------------------------
  gemm_qkvs<bf16,bf16><<<gm64,256,0,stream>>>(Hb,
      (const short8v*)Wp[1][0], (const short8v*)Wp[1][1],
      (const short8v*)Wp[1][2], (const short8v*)Wp[1][3],
      Bw[1][0], Bw[1][1], Bw[1][2], Bw[1][3],
      q2, k2, v2, H2b, 256, 4, 0, 64, 64, 0, MP);
  fused_attn<64,8,bf16><<<NN/4,256,0,stream>>>(q2,k2,v2, SRCS,OFFS, H2b,64,0,
                                               LOG,Mx,Dn, s8);
  alpha8_k<<<NE*8/256,256,0,stream>>>(LOG, Mx, Dn, ei, PERM, out_at);
  gelu_ln<1><<<NN/4,256,0,stream>>>(H2b, lng[1], lnb[1]);

  // fc on h2 (independent of L3/L4)
  fc_k<<<NN/4,256,0,stream>>>(H2b, fcW, fcB, out_x, 64, 10);

  // ---- L3: 64 -> 256, H=8 (two 4-head col tiles) ---------------------------
  for (int col = 0; col <= 128; col += 128){
    int tg0 = col >> 4;
    gemm_qkvs<bf16,bf16><<<gm128,256,0,stream>>>(H2b,
        (const short8v*)Wp[2][0], (const short8v*)Wp[2][1],
        (const short8v*)Wp[2][2], (const short8v*)Wp[2][3],
        Bw[2][0]+col, Bw[2][1]+col, Bw[2][2]+col, Bw[2][3]+col,
        Qc, Kc, Vc, Hb, 64, 16, tg0, 128, 256, col, MP);
    fused_attn<128,4,bf16><<<NN/4,256,0,stream>>>(Qc,Kc,Vc, SRCS,OFFS, Hb,256,col,
                                                  nullptr,nullptr,nullptr, s32);
  }
  gelu_ln<4><<<NN/4,256,0,stream>>>(Hb, lng[2], lnb[2]);

  // ---- L4: 256 -> 128, H=1; skip accumulates f32 in out_h4 -----------------
  gemm_qkvs<bf16,float><<<gm128,256,0,stream>>>(Hb,
      (const short8v*)Wp[3][0], (const short8v*)Wp[3][1],
      (const short8v*)Wp[3][2], (const short8v*)Wp[3][3],
      Bw[3][0], Bw[3][1], Bw[3][2], Bw[3][3],
      Qc, Kc, Vc, out_h4, 256, 8, 0, 128, 128, 0, NN);
  fused_attn<128,1,float><<<NN/4,256,0,stream>>>(Qc,Kc,Vc, SRCS,OFFS, out_h4,128,0,
                                                 nullptr,nullptr,nullptr, s128);
  gelu_ln<2><<<NN/4,256,0,stream>>>(out_h4, lng[3], lnb[3]);
}

// Round 11
// 364.385 us; speedup vs baseline: 14.2547x; 1.0927x over previous
//
#include <hip/hip_runtime.h>
#include <hip/hip_bf16.h>
#include <math.h>

#define NN 20000
#define MP 20032            // NN padded to 64 (MFMA row tiles)
#define NE 320000

typedef __hip_bfloat16 bf16;
typedef __attribute__((ext_vector_type(8))) short short8v;   // 8 bf16 (4 VGPR)
typedef __attribute__((ext_vector_type(4))) short short4v;
typedef __attribute__((ext_vector_type(4))) float f32x4;

__device__ __forceinline__ float b2f(bf16 v){ return __bfloat162float(v); }
__device__ __forceinline__ bf16 f2b(float v){ return __float2bfloat16(v); }
__device__ __forceinline__ float bfbits(short s){
  return __uint_as_float(((unsigned)(unsigned short)s) << 16);
}
__device__ __forceinline__ int clampi(int v, int lo, int hi){ return v < lo ? lo : (v > hi ? hi : v); }
__device__ __forceinline__ void stv(bf16* p, float v){ *p = f2b(v); }
__device__ __forceinline__ void stv(float* p, float v){ *p = v; }
__device__ __forceinline__ float ldv(const bf16* p){ return b2f(*p); }
__device__ __forceinline__ float ldv(const float* p){ return *p; }

// vector row loader: CPL consecutive bf16 -> f32
template<int CPL>
__device__ __forceinline__ void ldrow(const bf16* p, float* o){
  if constexpr (CPL == 16){
    short8v v0 = *reinterpret_cast<const short8v*>(p);
    short8v v1 = *reinterpret_cast<const short8v*>(p + 8);
#pragma unroll
    for (int j = 0; j < 8; j++){ o[j] = bfbits(v0[j]); o[8+j] = bfbits(v1[j]); }
  } else if constexpr (CPL == 8){
    short8v v = *reinterpret_cast<const short8v*>(p);
#pragma unroll
    for (int j = 0; j < 8; j++) o[j] = bfbits(v[j]);
  } else {
    short4v v = *reinterpret_cast<const short4v*>(p);
#pragma unroll
    for (int j = 0; j < 4; j++) o[j] = bfbits(v[j]);
  }
}

// A-fragment loaders (8 consecutive-k elems per lane)
__device__ __forceinline__ short8v ldA8(const bf16* p){
  return *reinterpret_cast<const short8v*>(p);
}
__device__ __forceinline__ short8v ldA8(const float* p){
  float4 a0 = *reinterpret_cast<const float4*>(p);
  float4 a1 = *reinterpret_cast<const float4*>(p + 4);
  short8v r;
  bf16 b;
  b = f2b(a0.x); r[0] = *(const short*)&b;
  b = f2b(a0.y); r[1] = *(const short*)&b;
  b = f2b(a0.z); r[2] = *(const short*)&b;
  b = f2b(a0.w); r[3] = *(const short*)&b;
  b = f2b(a1.x); r[4] = *(const short*)&b;
  b = f2b(a1.y); r[5] = *(const short*)&b;
  b = f2b(a1.z); r[6] = *(const short*)&b;
  b = f2b(a1.w); r[7] = *(const short*)&b;
  return r;
}

// ---- diagnostic fill ------------------------------------------------------
__global__ void fill_k(float* __restrict__ out, int n, float val){
  int i = blockIdx.x*blockDim.x + threadIdx.x;
  if (i < n) out[i] = val;
}

// ---- all-weights pack: f32 [K x D] -> MFMA B-fragment order bf16 -----------
struct PackArgs {
  const float* w[16];
  unsigned long long off[16];
  int K[16];
  int D[16];
};
__global__ void pack_all(PackArgs pa, bf16* __restrict__ out){
  int wi = blockIdx.y;
  int K = pa.K[wi], D = pa.D[wi];
  int i = blockIdx.x*256 + threadIdx.x;
  if (i >= K*D) return;
  int j = i & 7, l = (i >> 3) & 63;
  int TG = D >> 4;
  int tg = (i >> 9) % TG, s = (i >> 9) / TG;
  int k = s*32 + (l >> 4)*8 + j, n = tg*16 + (l & 15);
  out[pa.off[wi] + i] = f2b(pa.w[wi][(size_t)k*D + n]);
}

// ---- fused QKVS MFMA GEMM: 4 outputs sharing the A matrix ------------------
template<typename AT, typename TS>
__global__ void gemm_qkvs(const AT* __restrict__ X,
    const short8v* __restrict__ WQ, const short8v* __restrict__ WK,
    const short8v* __restrict__ WV, const short8v* __restrict__ WS,
    const float* __restrict__ bQ, const float* __restrict__ bK,
    const float* __restrict__ bV, const float* __restrict__ bS,
    bf16* __restrict__ Qo, bf16* __restrict__ Ko, bf16* __restrict__ Vo,
    TS* __restrict__ So,
    int K, int TG, int ldQKV, int ldS, int MstoreS){
  int w = threadIdx.x >> 6, lane = threadIdx.x & 63;
  int n0 = blockIdx.x*64;
  size_t m0 = (size_t)blockIdx.y*64 + w*16;
  int lr = lane & 15, lk = lane >> 4;
  int ar = clampi((int)(m0 + lr), 0, NN-1);
  const AT* xp = X + (size_t)ar*K + lk*8;
  size_t wo = ((size_t)(n0 >> 4))*64 + lane;
  f32x4 acc[4][4];
#pragma unroll
  for (int j = 0; j < 4; j++)
#pragma unroll
    for (int t = 0; t < 4; t++) acc[j][t] = f32x4{0,0,0,0};
  int steps = K >> 5;
  for (int s = 0; s < steps; s++){
    short8v a = ldA8(xp + s*32);
    size_t ro = wo + (size_t)s*TG*64;
#pragma unroll
    for (int t = 0; t < 4; t++){
      size_t idx = ro + t*64;
      acc[0][t] = __builtin_amdgcn_mfma_f32_16x16x32_bf16(a, WQ[idx], acc[0][t], 0, 0, 0);
      acc[1][t] = __builtin_amdgcn_mfma_f32_16x16x32_bf16(a, WK[idx], acc[1][t], 0, 0, 0);
      acc[2][t] = __builtin_amdgcn_mfma_f32_16x16x32_bf16(a, WV[idx], acc[2][t], 0, 0, 0);
      acc[3][t] = __builtin_amdgcn_mfma_f32_16x16x32_bf16(a, WS[idx], acc[3][t], 0, 0, 0);
    }
  }
#pragma unroll
  for (int t = 0; t < 4; t++){
    int col = n0 + t*16 + lr;
    float b0 = bQ[col], b1 = bK[col], b2 = bV[col], b3 = bS[col];
#pragma unroll
    for (int r = 0; r < 4; r++){
      size_t row = m0 + lk*4 + r;
      Qo[row*ldQKV + col] = f2b(acc[0][t][r] + b0);
      Ko[row*ldQKV + col] = f2b(acc[1][t][r] + b1);
      Vo[row*ldQKV + col] = f2b(acc[2][t][r] + b2);
      if ((int)row < MstoreS) stv(&So[row*(size_t)ldS + col], acc[3][t][r] + b3);
    }
  }
}

// ---- CSR build -------------------------------------------------------------
__global__ void count_k(const int* __restrict__ ei, int* __restrict__ cnt, int E){
  int e = blockIdx.x*blockDim.x + threadIdx.x;
  if (e < E){
    int d = clampi(ei[E + e], 0, NN-1);
    atomicAdd(&cnt[d], 1);
  }
}

__global__ void exscan_k(const int* __restrict__ cnt, int* __restrict__ off,
                         int* __restrict__ cur, int n){
  __shared__ int wtot[16];
  __shared__ int carrysh;
  int tid = threadIdx.x, lane = tid & 63, w = tid >> 6;
  if (tid == 0) carrysh = 0;
  __syncthreads();
  for (int base = 0; base < n; base += 1024){
    int i = base + tid;
    int v = (i < n) ? cnt[i] : 0;
    int s = v;
#pragma unroll
    for (int d = 1; d < 64; d <<= 1){
      int t = __shfl_up(s, d);
      if (lane >= d) s += t;
    }
    if (lane == 63) wtot[w] = s;
    __syncthreads();
    int woff = 0;
    for (int j = 0; j < w; j++) woff += wtot[j];
    int c = carrysh;
    if (i < n){ int val = c + woff + s - v; off[i] = val; cur[i] = val; }
    __syncthreads();
    if (tid == 1023) carrysh = c + woff + s;
    __syncthreads();
  }
  if (threadIdx.x == 0) off[n] = carrysh;
}

__global__ void scatter_k(const int* __restrict__ ei, int* __restrict__ cur,
                          int* __restrict__ perm, int* __restrict__ srcs, int E){
  int e = blockIdx.x*blockDim.x + threadIdx.x;
  if (e >= E) return;
  int s = clampi(ei[e], 0, NN-1);
  int d = clampi(ei[E + e], 0, NN-1);
  int p = atomicAdd(&cur[d], 1);
  if (p >= 0 && p < E){ perm[p] = e; srcs[p] = s; }
}

// ---- fused per-node attention: quad-edge quarter-waves + prefetch ----------
template<int D, int H, typename TO>
__global__ void fused_attn(const bf16* __restrict__ Q, const bf16* __restrict__ Kf,
                           const bf16* __restrict__ V, const int* __restrict__ srcs,
                           const int* __restrict__ offs,
                           TO* __restrict__ Xout, int ldO,
                           bf16* __restrict__ LOG, float* __restrict__ MxO,
                           float* __restrict__ DnO, float scale){
  constexpr int CPL = D/16;       // channels per lane (quarter-wave of 16)
  constexpr int LPH = 16/H;       // lanes per head within a slot
  int node = blockIdx.x*4 + (threadIdx.x >> 6);
  if (node >= NN) return;
  int lane = threadIdx.x & 63;
  int hl = lane & 15;
  int slot = lane >> 4;
  float q[CPL];
  {
    float tmp[CPL];
    ldrow<CPL>(Q + (size_t)node*D + hl*CPL, tmp);
#pragma unroll
    for (int j = 0; j < CPL; j++) q[j] = tmp[j] * scale;
  }
  float m = -INFINITY, den = 0.f;
  float acc[CPL];
#pragma unroll
  for (int j = 0; j < CPL; j++) acc[j] = 0.f;
  int s0 = offs[node], e0 = offs[node+1];
  int i = s0 + slot;
  bool vcur = i < e0;
  int sc = vcur ? srcs[i] : 0;
  float kc[CPL], vc[CPL];
  ldrow<CPL>(Kf + (size_t)sc*D + hl*CPL, kc);
  ldrow<CPL>(V  + (size_t)sc*D + hl*CPL, vc);
  int iters = (e0 - s0 + 3) >> 2;
  for (int it = 0; it < iters; ++it){
    int inext = i + 4;
    bool vnxt = inext < e0;
    int sn = vnxt ? srcs[inext] : 0;
    float kn[CPL], vn[CPL];
    ldrow<CPL>(Kf + (size_t)sn*D + hl*CPL, kn);
    ldrow<CPL>(V  + (size_t)sn*D + hl*CPL, vn);
    float t = 0.f;
#pragma unroll
    for (int j = 0; j < CPL; j++) t += q[j]*kc[j];
#pragma unroll
    for (int o = 1; o < LPH; o <<= 1) t += __shfl_xor(t, o);
    if (!vcur) t = -INFINITY;
    if (LOG && vcur && ((hl & (LPH-1)) == 0)) LOG[(size_t)i*H + hl/LPH] = f2b(t);
    float tm = fmaxf(t, __shfl_xor(t, 16));
    tm = fmaxf(tm, __shfl_xor(tm, 32));
    float nm = fmaxf(m, tm);
    float fe = __expf(m - nm);
    float pe = __expf(t - nm);
    den = den*fe + pe;
#pragma unroll
    for (int j = 0; j < CPL; j++) acc[j] = acc[j]*fe + pe*vc[j];
    m = nm;
    vcur = vnxt; i = inext;
#pragma unroll
    for (int j = 0; j < CPL; j++){ kc[j] = kn[j]; vc[j] = vn[j]; }
  }
  den += __shfl_xor(den, 16);
  den += __shfl_xor(den, 32);
#pragma unroll
  for (int j = 0; j < CPL; j++){
    acc[j] += __shfl_xor(acc[j], 16);
    acc[j] += __shfl_xor(acc[j], 32);
  }
  float inv = 1.f/(den + 1e-16f);
  if (slot == 0){
    TO* o = Xout + (size_t)node*ldO + hl*CPL;
#pragma unroll
    for (int j = 0; j < CPL; j++) stv(&o[j], ldv(&o[j]) + acc[j]*inv);
    if (MxO && ((hl & (LPH-1)) == 0)){
      MxO[node*H + hl/LPH] = m;
      DnO[node*H + hl/LPH] = den;
    }
  }
}

// ---- alpha scatter for L2 --------------------------------------------------
__global__ void alpha8_k(const bf16* __restrict__ LOG, const float* __restrict__ Mx,
                         const float* __restrict__ Dn, const int* __restrict__ ei,
                         const int* __restrict__ perm, float* __restrict__ attn){
  size_t t = (size_t)blockIdx.x*blockDim.x + threadIdx.x;
  if (t >= (size_t)NE*8) return;
  int pos = (int)(t >> 3), h = (int)(t & 7);
  int e = perm[pos];
  int node = ei[NE + e];
  float a = __expf(b2f(LOG[t]) - Mx[node*8 + h]) / (Dn[node*8 + h] + 1e-16f);
  attn[(size_t)e*8 + h] = a;
}

// ---- fused exact-GELU + LayerNorm, in place --------------------------------
template<int CPL, typename T>
__global__ void gelu_ln(T* __restrict__ X, const float* __restrict__ G,
                        const float* __restrict__ Bt){
  int node = blockIdx.x*4 + (threadIdx.x >> 6);
  if (node >= NN) return;
  constexpr int D = CPL*64;
  int lane = threadIdx.x & 63;
  T* xr = X + (size_t)node*D + lane*CPL;
  float v[CPL]; float s = 0.f;
#pragma unroll
  for (int j = 0; j < CPL; j++){
    float t = ldv(&xr[j]);
    float ge = 0.5f*t*(1.f + erff(t*0.70710678118654752f));
    v[j] = ge; s += ge;
  }
#pragma unroll
  for (int off = 1; off < 64; off <<= 1) s += __shfl_xor(s, off);
  float mu = s * (1.f/D);
  float q = 0.f;
#pragma unroll
  for (int j = 0; j < CPL; j++){ float d = v[j]-mu; q += d*d; }
#pragma unroll
  for (int off = 1; off < 64; off <<= 1) q += __shfl_xor(q, off);
  float inv = 1.f / sqrtf(q*(1.f/D) + 1e-5f);
#pragma unroll
  for (int j = 0; j < CPL; j++){
    int c = lane*CPL + j;
    stv(&xr[j], G[c]*(v[j]-mu)*inv + Bt[c]);
  }
}

// ---- tiny fc ----------------------------------------------------------------
__global__ void fc_k(const bf16* __restrict__ X, const float* __restrict__ W,
                     const float* __restrict__ B, float* __restrict__ Out,
                     int K, int D){
  int m = blockIdx.x*4 + (threadIdx.x >> 6);
  int lane = threadIdx.x & 63;
  if (m >= NN || lane >= D) return;
  float acc = B[lane];
  for (int k = 0; k < K; k++) acc += b2f(X[(size_t)m*K + k]) * W[(size_t)k*D + lane];
  Out[(size_t)m*D + lane] = acc;
}

extern "C" void kernel_launch(void* const* d_in, const int* in_sizes, int n_in,
                              void* d_out, int out_size, void* d_ws, size_t ws_size,
                              hipStream_t stream){
  int code = 0;
  if (n_in != 44) code = 100;
  else {
    const int wsz[4] = {32768,16384,16384,32768};
    const int bsz[4] = {256,64,256,128};
    bool ok = in_sizes[0] == NN*128 && in_sizes[1] == 2*NE
           && in_sizes[42] == 640 && in_sizes[43] == 10;
    for (int l = 0; l < 4 && ok; l++){
      for (int j = 0; j < 4; j++)
        ok = ok && in_sizes[2+l*8+j] == wsz[l] && in_sizes[2+l*8+4+j] == bsz[l];
      ok = ok && in_sizes[34+2*l] == bsz[l] && in_sizes[35+2*l] == bsz[l];
    }
    if (!ok) code = 140;
  }
  if (code){
    fill_k<<<((size_t)out_size+255)/256, 256, 0, stream>>>((float*)d_out, out_size, (float)code);
    return;
  }

  const float* x = (const float*)d_in[0];
  const int*   ei = (const int*)d_in[1];
  const float *W[4][4], *Bw[4][4], *lng[4], *lnb[4];
  for (int l = 0; l < 4; l++){
    for (int j = 0; j < 4; j++){
      W[l][j]  = (const float*)d_in[2 + l*8 + j];      // Wq,Wk,Wv,Ws
      Bw[l][j] = (const float*)d_in[2 + l*8 + 4 + j];  // bq,bk,bv,bs
    }
    lng[l] = (const float*)d_in[34 + 2*l];
    lnb[l] = (const float*)d_in[35 + 2*l];
  }
  const float* fcW = (const float*)d_in[42];
  const float* fcB = (const float*)d_in[43];

  // ---- workspace (~52 MB of ~256 MiB) --------------------------------------
  char* ws = (char*)d_ws;
  size_t o = 0;
  auto alloc = [&](size_t bytes)->void*{ void* p = ws + o; o += (bytes + 255)/256*256; return p; };
  bf16* Hb   = (bf16*)alloc((size_t)MP*256*2);
  bf16* H2b  = (bf16*)alloc((size_t)MP*64*2);
  bf16* Qb   = (bf16*)alloc((size_t)MP*256*2);
  bf16* Kb   = (bf16*)alloc((size_t)MP*256*2);
  bf16* Vb   = (bf16*)alloc((size_t)MP*256*2);
  bf16* LOG  = (bf16*)alloc((size_t)NE*8*2);
  float* Mx  = (float*)alloc((size_t)NN*8*4);
  float* Dn  = (float*)alloc((size_t)NN*8*4);
  int* OFFS  = (int*)alloc((size_t)(NN+1)*4);
  int* CNT   = (int*)alloc((size_t)(NN+1)*4);
  int* CURS  = (int*)alloc((size_t)(NN+1)*4);
  int* PERM  = (int*)alloc((size_t)NE*4);
  int* SRCS  = (int*)alloc((size_t)NE*4);
  bf16* WPK  = (bf16*)alloc((size_t)393216*2);
  size_t need = o;

  float* out_x  = (float*)d_out;                 // [NN,10]
  float* out_h4 = out_x + (size_t)NN*10;         // [NN,128]
  float* out_at = out_h4 + (size_t)NN*128;       // [NE,8]

  if (ws_size < need){
    fill_k<<<((size_t)out_size+255)/256, 256, 0, stream>>>((float*)d_out, out_size, 160.0f);
    return;
  }

  // ---- pack all 16 weights in ONE launch -----------------------------------
  const int KD[4] = {128,256,64,256};
  const int DD[4] = {256,64,256,128};
  PackArgs pa;
  bf16* Wp[4][4];
  {
    size_t off = 0;
    for (int l = 0; l < 4; l++)
      for (int j = 0; j < 4; j++){
        int idx = l*4 + j;
        pa.w[idx] = W[l][j];
        pa.off[idx] = off;
        pa.K[idx] = KD[l];
        pa.D[idx] = DD[l];
        Wp[l][j] = WPK + off;
        off += (size_t)KD[l]*DD[l];
      }
  }
  pack_all<<<dim3(128,16),256,0,stream>>>(pa, WPK);

  // ---- CSR by dst (4 launches) ---------------------------------------------
  hipMemsetAsync(CNT, 0, (size_t)NN*4, stream);
  count_k<<<NE/256, 256, 0, stream>>>(ei, CNT, NE);
  exscan_k<<<1, 1024, 0, stream>>>(CNT, OFFS, CURS, NN);
  scatter_k<<<NE/256, 256, 0, stream>>>(ei, CURS, PERM, SRCS, NE);

  const float s32  = 0.1767766952966369f;
  const float s8   = 0.3535533905932738f;
  const float s128 = 0.0883883476483184f;
  const dim3 g64(1, MP/64), g128(2, MP/64), g256(4, MP/64);

  // ---- L1: 128 -> 256, H=8 (full width, one pass) --------------------------
  gemm_qkvs<float,bf16><<<g256,256,0,stream>>>(x,
      (const short8v*)Wp[0][0], (const short8v*)Wp[0][1],
      (const short8v*)Wp[0][2], (const short8v*)Wp[0][3],
      Bw[0][0], Bw[0][1], Bw[0][2], Bw[0][3],
      Qb, Kb, Vb, Hb, 128, 16, 256, 256, MP);
  fused_attn<256,8,bf16><<<NN/4,256,0,stream>>>(Qb,Kb,Vb, SRCS,OFFS, Hb,256,
                                                nullptr,nullptr,nullptr, s32);
  gelu_ln<4><<<NN/4,256,0,stream>>>(Hb, lng[0], lnb[0]);

  // ---- L2: 256 -> 64, H=8 (emits attn) -------------------------------------
  gemm_qkvs<bf16,bf16><<<g64,256,0,stream>>>(Hb,
      (const short8v*)Wp[1][0], (const short8v*)Wp[1][1],
      (const short8v*)Wp[1][2], (const short8v*)Wp[1][3],
      Bw[1][0], Bw[1][1], Bw[1][2], Bw[1][3],
      Qb, Kb, Vb, H2b, 256, 4, 64, 64, MP);
  fused_attn<64,8,bf16><<<NN/4,256,0,stream>>>(Qb,Kb,Vb, SRCS,OFFS, H2b,64,
                                               LOG,Mx,Dn, s8);
  alpha8_k<<<NE*8/256,256,0,stream>>>(LOG, Mx, Dn, ei, PERM, out_at);
  gelu_ln<1><<<NN/4,256,0,stream>>>(H2b, lng[1], lnb[1]);

  // fc on h2 (independent of L3/L4)
  fc_k<<<NN/4,256,0,stream>>>(H2b, fcW, fcB, out_x, 64, 10);

  // ---- L3: 64 -> 256, H=8 (full width, one pass) ---------------------------
  gemm_qkvs<bf16,bf16><<<g256,256,0,stream>>>(H2b,
      (const short8v*)Wp[2][0], (const short8v*)Wp[2][1],
      (const short8v*)Wp[2][2], (const short8v*)Wp[2][3],
      Bw[2][0], Bw[2][1], Bw[2][2], Bw[2][3],
      Qb, Kb, Vb, Hb, 64, 16, 256, 256, MP);
  fused_attn<256,8,bf16><<<NN/4,256,0,stream>>>(Qb,Kb,Vb, SRCS,OFFS, Hb,256,
                                                nullptr,nullptr,nullptr, s32);
  gelu_ln<4><<<NN/4,256,0,stream>>>(Hb, lng[2], lnb[2]);

  // ---- L4: 256 -> 128, H=1; skip accumulates f32 in out_h4 -----------------
  gemm_qkvs<bf16,float><<<g128,256,0,stream>>>(Hb,
      (const short8v*)Wp[3][0], (const short8v*)Wp[3][1],
      (const short8v*)Wp[3][2], (const short8v*)Wp[3][3],
      Bw[3][0], Bw[3][1], Bw[3][2], Bw[3][3],
      Qb, Kb, Vb, out_h4, 256, 8, 128, 128, NN);
  fused_attn<128,1,float><<<NN/4,256,0,stream>>>(Qb,Kb,Vb, SRCS,OFFS, out_h4,128,
                                                 nullptr,nullptr,nullptr, s128);
  gelu_ln<2><<<NN/4,256,0,stream>>>(out_h4, lng[3], lnb[3]);
}